// Round 7
// baseline (1285.310 us; speedup 1.0000x reference)
//
#include <hip/hip_runtime.h>

#define N_NODES 100000
#define N_EDGES 800000
#define NB 100
#define NL 4
#define QM 32
#define EPS_BN 1e-5f
#define NTILE 782      // ceil(N_NODES / 128)
#define NBLK_MLP 782   // one 128-row tile per block; 4 blocks/CU guaranteed resident

typedef __bf16 bf16_t;
typedef __bf16 bf16x8 __attribute__((ext_vector_type(8)));
typedef __bf16 bf16x4 __attribute__((ext_vector_type(4)));
typedef __bf16 bf16x2 __attribute__((ext_vector_type(2)));
typedef float f32x4 __attribute__((ext_vector_type(4)));

// ---------------- setup: counting sort by dst ----------------

__global__ void k_count(const int* __restrict__ dst, int* __restrict__ counts) {
    int e = blockIdx.x * 256 + threadIdx.x;
    if (e < N_EDGES) atomicAdd(&counts[dst[e]], 1);
}

__global__ void k_scan1(const int* __restrict__ counts, int* __restrict__ row_ptr,
                        int* __restrict__ blk) {
    __shared__ int s[1024];
    int i = blockIdx.x * 1024 + threadIdx.x;
    int v = (i < N_NODES) ? counts[i] : 0;
    s[threadIdx.x] = v;
    __syncthreads();
    for (int off = 1; off < 1024; off <<= 1) {
        int u = (threadIdx.x >= off) ? s[threadIdx.x - off] : 0;
        __syncthreads();
        s[threadIdx.x] += u;
        __syncthreads();
    }
    if (i < N_NODES) row_ptr[i] = s[threadIdx.x] - v;   // block-local exclusive
    if (threadIdx.x == 1023) blk[blockIdx.x] = s[1023]; // block total
}

__global__ void k_scan2(int* __restrict__ blk) { // exclusive scan of 98 block totals
    __shared__ int s[128];
    int t = threadIdx.x;
    int v = (t < 98) ? blk[t] : 0;
    s[t] = v;
    __syncthreads();
    for (int off = 1; off < 128; off <<= 1) {
        int u = (t >= off) ? s[t - off] : 0;
        __syncthreads();
        s[t] += u;
        __syncthreads();
    }
    if (t < 98) blk[t] = s[t] - v;
}

__global__ void k_scan3(const int* __restrict__ blk, int* __restrict__ row_ptr) {
    int i = blockIdx.x * 1024 + threadIdx.x;
    if (i < N_NODES) row_ptr[i] += blk[blockIdx.x];
    if (i == 0) row_ptr[N_NODES] = N_EDGES;
}

// one scattered 16B write per edge: edat[pos] = {src, dst, graph, orig_e}
__global__ void k_scatter(const int* __restrict__ ei, const int* __restrict__ batch,
                          const int* __restrict__ row_ptr, int* __restrict__ cursor,
                          int4* __restrict__ edat) {
    int e = blockIdx.x * 256 + threadIdx.x;
    if (e >= N_EDGES) return;
    int s = ei[e], d = ei[N_EDGES + e];
    int pos = row_ptr[d] + atomicAdd(&cursor[d], 1);
    edat[pos] = make_int4(s, d, batch[s], e);
}

// gather-style: indexed by sorted slot p (coalesced writes), gathered reads.
// feat[p] = [z_re(32) | z_im(32) | ea(64)] bf16. 16 lanes per edge, 2 edges per
// group for doubled memory-level parallelism (all 6 gathers in flight at once).
__global__ void k_permute(const float* __restrict__ pe, const float* __restrict__ ea,
                          const int4* __restrict__ edat, bf16_t* __restrict__ feat) {
    int t = blockIdx.x * 256 + threadIdx.x;
    int g = t >> 4, k = t & 15;
    size_t p0 = (size_t)g << 1;
    int4 ed0 = edat[p0];
    int4 ed1 = edat[p0 + 1];
    f32x4 s0 = *(const f32x4*)(pe + (size_t)ed0.x * 64 + k * 4);
    f32x4 d0 = *(const f32x4*)(pe + (size_t)ed0.y * 64 + k * 4);
    f32x4 a0 = *(const f32x4*)(ea + (size_t)ed0.w * 64 + k * 4);
    f32x4 s1 = *(const f32x4*)(pe + (size_t)ed1.x * 64 + k * 4);
    f32x4 d1 = *(const f32x4*)(pe + (size_t)ed1.y * 64 + k * 4);
    f32x4 a1 = *(const f32x4*)(ea + (size_t)ed1.w * 64 + k * 4);

    bf16x4 ao0, ao1;
#pragma unroll
    for (int i = 0; i < 4; i++) { ao0[i] = (bf16_t)a0[i]; ao1[i] = (bf16_t)a1[i]; }
    bf16x2 re0, im0, re1, im1;
    re0[0] = (bf16_t)(s0[0] * d0[0] + s0[1] * d0[1]);
    re0[1] = (bf16_t)(s0[2] * d0[2] + s0[3] * d0[3]);
    im0[0] = (bf16_t)(s0[1] * d0[0] - s0[0] * d0[1]);
    im0[1] = (bf16_t)(s0[3] * d0[2] - s0[2] * d0[3]);
    re1[0] = (bf16_t)(s1[0] * d1[0] + s1[1] * d1[1]);
    re1[1] = (bf16_t)(s1[2] * d1[2] + s1[3] * d1[3]);
    im1[0] = (bf16_t)(s1[1] * d1[0] - s1[0] * d1[1]);
    im1[1] = (bf16_t)(s1[3] * d1[2] - s1[2] * d1[3]);

    bf16_t* f0 = feat + p0 * 128;
    *(bf16x2*)(f0 + 2 * k) = re0;
    *(bf16x2*)(f0 + 32 + 2 * k) = im0;
    *(bf16x4*)(f0 + 64 + 4 * k) = ao0;
    bf16_t* f1 = f0 + 128;
    *(bf16x2*)(f1 + 2 * k) = re1;
    *(bf16x2*)(f1 + 32 + 2 * k) = im1;
    *(bf16x4*)(f1 + 64 + 4 * k) = ao1;
}

// ---------------- weight prep ----------------

__global__ void k_phi(const float* __restrict__ Lam, const float* __restrict__ w1,
                      const float* __restrict__ b1, const float* __restrict__ w2,
                      const float* __restrict__ b2, bf16_t* __restrict__ w_all) {
    int idx = blockIdx.x * 256 + threadIdx.x;
    if (idx >= NL * NB * QM) return;
    int l = idx / (NB * QM);
    int rem = idx % (NB * QM);
    float lam = Lam[rem];
    float acc = b2[l];
    for (int i = 0; i < 16; i++) {
        float h = lam * w1[l * 16 + i] + b1[l * 16 + i];
        acc += fmaxf(h, 0.f) * w2[l * 16 + i];
    }
    w_all[idx] = (bf16_t)acc;
}

__global__ void k_prep(const float* __restrict__ enc_w, const float* __restrict__ enc_b,
                       const float* __restrict__ lin_w, const float* __restrict__ lin_b,
                       const float* __restrict__ mlp_w1, const float* __restrict__ mlp_w2,
                       bf16_t* __restrict__ wcat_frag, bf16_t* __restrict__ w1frag,
                       bf16_t* __restrict__ w2frag, float* __restrict__ cvec) {
    __shared__ float lds[128][64];
    int l = blockIdx.x, tid = threadIdx.x;
    const float* ew = enc_w + l * 64 * 64;
    const float* lw = lin_w + l * 64 * 64;
    for (int idx = tid; idx < 64 * 64; idx += 256) {
        int r = idx >> 6, c = idx & 63;
        float acc = 0.f;
        for (int k = 0; k < 64; k++) acc += ew[r * 64 + k] * lw[k * 64 + c];
        lds[r][c] = acc;
        lds[64 + r][c] = lw[r * 64 + c];
    }
    if (tid < 64) {
        float acc = lin_b[l * 64 + tid];
        for (int k = 0; k < 64; k++) acc += enc_b[l * 64 + k] * lw[k * 64 + tid];
        cvec[l * 64 + tid] = acc;
    }
    __syncthreads();
    for (int idx = tid; idx < 16 * 512; idx += 256) {
        int sn = idx >> 9, lane = (idx >> 3) & 63, j = idx & 7;
        int s = sn >> 2, nt = sn & 3;
        int row = 32 * s + (lane >> 4) * 8 + j;
        int col = 16 * nt + (lane & 15);
        wcat_frag[l * 8192 + idx] = (bf16_t)lds[row][col];
    }
    for (int idx = tid; idx < 8 * 512; idx += 256) {
        int sn = idx >> 9, lane = (idx >> 3) & 63, j = idx & 7;
        int s = sn >> 2, nt = sn & 3;
        int row = 32 * s + (lane >> 4) * 8 + j; // k index
        int col = 16 * nt + (lane & 15);
        w1frag[l * 4096 + idx] = (bf16_t)mlp_w1[(l * 64 + row) * 64 + col];
        w2frag[l * 4096 + idx] = (bf16_t)mlp_w2[(l * 64 + row) * 64 + col];
    }
}

// ---------------- per-layer kernels ----------------

// layer 0 init: x_bf = bf16(x), h = x; also pe passthrough to out (replaces memcpy)
__global__ void k_hinit0(const float* __restrict__ x, const float* __restrict__ pe,
                         bf16_t* __restrict__ x_bf, float* __restrict__ h,
                         float* __restrict__ out_pe) {
    size_t i = ((size_t)blockIdx.x * 256 + threadIdx.x) * 8;
    f32x4 a = *(const f32x4*)(x + i), b = *(const f32x4*)(x + i + 4);
    *(f32x4*)(h + i) = a;
    *(f32x4*)(h + i + 4) = b;
    bf16x8 o;
#pragma unroll
    for (int k = 0; k < 4; k++) { o[k] = (bf16_t)a[k]; o[k + 4] = (bf16_t)b[k]; }
    *(bf16x8*)(x_bf + i) = o;
    f32x4 p0 = *(const f32x4*)(pe + i), p1 = *(const f32x4*)(pe + i + 4);
    *(f32x4*)(out_pe + i) = p0;
    *(f32x4*)(out_pe + i + 4) = p1;
}

// 128 dst-sorted edges per block: msg = relu(x[src] + feat @ Wcat + cvec),
// then in-block segment sum into h (h pre-initialized to x).
__global__ void k_edge(const bf16_t* __restrict__ feat, const int4* __restrict__ edat,
                       const int* __restrict__ row_ptr, const bf16_t* __restrict__ w_l,
                       const bf16_t* __restrict__ wcat_l, const float* __restrict__ cvec_l,
                       const bf16_t* __restrict__ x_bf, float* __restrict__ h) {
    __shared__ float msg[128][68];
    int tid = threadIdx.x;
    int wave = tid >> 6, lane = tid & 63;
    int quad = lane >> 4, l16 = lane & 15;
    int e0 = blockIdx.x * 128;

    bf16x8 bfrag[4][4];
    const bf16x8* wf = (const bf16x8*)wcat_l;
#pragma unroll
    for (int s = 0; s < 4; s++)
#pragma unroll
        for (int nt = 0; nt < 4; nt++) bfrag[s][nt] = wf[(s * 4 + nt) * 64 + lane];

    f32x4 acc[2][4];
#pragma unroll
    for (int rt = 0; rt < 2; rt++)
#pragma unroll
        for (int nt = 0; nt < 4; nt++) acc[rt][nt] = (f32x4)(0.f);

    int em[2];
    bf16x8 wch[2];
#pragma unroll
    for (int rt = 0; rt < 2; rt++) {
        em[rt] = e0 + wave * 32 + rt * 16 + l16;
        int eg = edat[em[rt]].z;
        wch[rt] = *(const bf16x8*)(w_l + (size_t)eg * QM + quad * 8);
    }
#pragma unroll
    for (int s = 0; s < 4; s++) {
        bf16x8 afr[2];
#pragma unroll
        for (int rt = 0; rt < 2; rt++) {
            bf16x8 v = *(const bf16x8*)(feat + (size_t)em[rt] * 128 + s * 32 + quad * 8);
            if (s < 2) {
                bf16x8 a;
#pragma unroll
                for (int i = 0; i < 8; i++) a[i] = (bf16_t)((float)v[i] * (float)wch[rt][i]);
                afr[rt] = a;
            } else {
                afr[rt] = v;
            }
        }
#pragma unroll
        for (int rt = 0; rt < 2; rt++)
#pragma unroll
            for (int nt = 0; nt < 4; nt++)
                acc[rt][nt] = __builtin_amdgcn_mfma_f32_16x16x32_bf16(afr[rt], bfrag[s][nt],
                                                                     acc[rt][nt], 0, 0, 0);
    }
    // C layout: row = quad*4 + r, col = lane&15 (per 16x16 tile)
#pragma unroll
    for (int nt = 0; nt < 4; nt++) {
        float cv = cvec_l[nt * 16 + l16];
#pragma unroll
        for (int rt = 0; rt < 2; rt++)
#pragma unroll
            for (int r = 0; r < 4; r++)
                msg[wave * 32 + rt * 16 + quad * 4 + r][nt * 16 + l16] = acc[rt][nt][r] + cv;
    }
    __syncthreads();
    // add x[src] (bf16 row = 128B per 8-lane group), relu
#pragma unroll
    for (int it = 0; it < 4; it++) {
        int j = it * 32 + (tid >> 3);
        int l8 = tid & 7;
        int srcn = edat[e0 + j].x;
        bf16x8 xv = *(const bf16x8*)(x_bf + (size_t)srcn * 64 + l8 * 8);
        float* mrow = &msg[j][l8 * 8];
        f32x4 m0 = *(const f32x4*)mrow, m1 = *(const f32x4*)(mrow + 4);
#pragma unroll
        for (int k = 0; k < 4; k++) {
            m0[k] = fmaxf(m0[k] + (float)xv[k], 0.f);
            m1[k] = fmaxf(m1[k] + (float)xv[k + 4], 0.f);
        }
        *(f32x4*)mrow = m0;
        *(f32x4*)(mrow + 4) = m1;
    }
    __syncthreads();
    // segment reduce over this block's edge window
    int nfirst = edat[e0].y, nlast = edat[e0 + 127].y;
    int c = tid & 63;
    for (int n = nfirst + (tid >> 6); n <= nlast; n += 4) {
        int rs = row_ptr[n], re = row_ptr[n + 1];
        int a = rs > e0 ? rs : e0;
        int b = re < e0 + 128 ? re : e0 + 128;
        if (a >= b) continue;
        float sum = 0.f;
        for (int jj = a; jj < b; jj++) sum += msg[jj - e0][c];
        float* addr = h + (size_t)n * 64 + c;
        if (rs >= e0 && re <= e0 + 128) *addr += sum;  // sole owner
        else atomicAdd(addr, sum);                     // boundary node
    }
}

// ---- fused MLP: t = h@w1+b1 -> BN1 -> relu -> @w2+b2 -> BN2 [-> relu] ----
// One kernel, two grid barriers. Cross-block data (stats, bar) flows through
// device-scope atomics only -> RELEASE arrive + RELAXED spin (no cache-flush
// fences; an acquire-per-poll invalidates the XCD L2 every iteration -> the
// 60us/barrier regression seen in R4). One 128-row tile per block, 782 blocks
// at 4 blocks/CU (launch_bounds(256,4), ~35KB LDS): 16 waves/CU hide the HBM
// latency of phase 1's direct-from-HBM MFMA feed (R5's 2 blocks/CU did not).
// t lives in swizzled LDS; h2 stays in VGPRs across the BN2 barrier; phase 3
// round-trips h2 through the dead LDS tile for coalesced stores.

__device__ __forceinline__ int swz_idx(int row, int col) {
    // bf16 element index with byte-XOR swizzle; keeps 16B alignment for b128 ops
    return ((row * 128 + col * 2) ^ ((row & 7) << 4)) >> 1;
}

__device__ __forceinline__ void gbar(int* bar, int target) {
    __syncthreads();
    if (threadIdx.x == 0) {
        __hip_atomic_fetch_add(bar, 1, __ATOMIC_RELEASE, __HIP_MEMORY_SCOPE_AGENT);
        while (__hip_atomic_load(bar, __ATOMIC_RELAXED, __HIP_MEMORY_SCOPE_AGENT) < target)
            __builtin_amdgcn_s_sleep(16);
    }
    __syncthreads();
}

template <int LAST>
__global__ __launch_bounds__(256, 4) void k_mlp(
    const float* __restrict__ h, const bf16_t* __restrict__ w1frag_l,
    const bf16_t* __restrict__ w2frag_l, const float* __restrict__ b1_l,
    const float* __restrict__ g1, const float* __restrict__ bb1,
    const float* __restrict__ b2_l, const float* __restrict__ g2,
    const float* __restrict__ bb2, float* __restrict__ stats1,
    float* __restrict__ stats2, int* __restrict__ bar, float* __restrict__ hout,
    bf16_t* __restrict__ x_bf, float* __restrict__ out) {
    // sbuf: phases 1-2 = one 128x64 bf16 t-tile (swizzled, 16KB);
    // phase 3 = one [128][68] f32 tile (h2 transpose for coalesced stores).
    __shared__ __align__(16) char sbuf[34816];
    __shared__ float sred[128];
    __shared__ float cf[128];
    bf16_t* tl = (bf16_t*)sbuf;
    float (*fls)[68] = (float(*)[68])sbuf;
    int tid = threadIdx.x, wave = tid >> 6, lane = tid & 63, quad = lane >> 4, l16 = lane & 15;
    int r0 = blockIdx.x * 128;

    bf16x8 bfrag[2][4];
    const bf16x8* wf1 = (const bf16x8*)w1frag_l;
#pragma unroll
    for (int s = 0; s < 2; s++)
#pragma unroll
        for (int nt = 0; nt < 4; nt++) bfrag[s][nt] = wf1[(s * 4 + nt) * 64 + lane];

    if (tid < 128) sred[tid] = 0.f;
    __syncthreads();

    // ---- phase 1: t-tile + BN1 stats ----
    {
        f32x4 acc[2][4];
#pragma unroll
        for (int rt = 0; rt < 2; rt++)
#pragma unroll
            for (int nt = 0; nt < 4; nt++) acc[rt][nt] = (f32x4)(0.f);
#pragma unroll
        for (int rt = 0; rt < 2; rt++) {
            int n = r0 + wave * 32 + rt * 16 + l16;
            bool valid = n < N_NODES;
#pragma unroll
            for (int s = 0; s < 2; s++) {
                bf16x8 a;
                if (valid) {
                    const float* hp = h + (size_t)n * 64 + s * 32 + quad * 8;
                    f32x4 v0 = *(const f32x4*)hp, v1 = *(const f32x4*)(hp + 4);
#pragma unroll
                    for (int i = 0; i < 4; i++) { a[i] = (bf16_t)v0[i]; a[i + 4] = (bf16_t)v1[i]; }
                } else {
#pragma unroll
                    for (int i = 0; i < 8; i++) a[i] = (bf16_t)0.f;
                }
#pragma unroll
                for (int nt = 0; nt < 4; nt++)
                    acc[rt][nt] = __builtin_amdgcn_mfma_f32_16x16x32_bf16(a, bfrag[s][nt],
                                                                         acc[rt][nt], 0, 0, 0);
            }
        }
#pragma unroll
        for (int nt = 0; nt < 4; nt++) {
            int col = nt * 16 + l16;
            float bias = b1_l[col];
            float s1 = 0.f, s2 = 0.f;
#pragma unroll
            for (int rt = 0; rt < 2; rt++)
#pragma unroll
                for (int r = 0; r < 4; r++) {
                    int rloc = wave * 32 + rt * 16 + quad * 4 + r;
                    int n = r0 + rloc;
                    if (n < N_NODES) {
                        float v = acc[rt][nt][r] + bias;
                        tl[swz_idx(rloc, col)] = (bf16_t)v;
                        s1 += v; s2 += v * v;
                    } else {
                        tl[swz_idx(rloc, col)] = (bf16_t)0.f;
                    }
                }
            s1 += __shfl_xor(s1, 16); s1 += __shfl_xor(s1, 32);
            s2 += __shfl_xor(s2, 16); s2 += __shfl_xor(s2, 32);
            if (quad == 0) { atomicAdd(&sred[col], s1); atomicAdd(&sred[64 + col], s2); }
        }
    }
    __syncthreads();
    if (tid < 128) atomicAdd(&stats1[tid], sred[tid]);
    gbar(bar, NBLK_MLP);

    // ---- phase 2: BN1 coefs, second GEMM (h2 stays in registers) ----
    if (tid < 128) sred[tid] = 0.f;
    if (tid < 64) {
        float sa = __hip_atomic_load(stats1 + tid, __ATOMIC_RELAXED, __HIP_MEMORY_SCOPE_AGENT);
        float sb = __hip_atomic_load(stats1 + 64 + tid, __ATOMIC_RELAXED, __HIP_MEMORY_SCOPE_AGENT);
        float mean = sa / (float)N_NODES;
        float var = sb / (float)N_NODES - mean * mean;
        float a = g1[tid] * rsqrtf(var + EPS_BN);
        cf[tid] = a;
        cf[64 + tid] = bb1[tid] - mean * a;
    }
    __syncthreads();

    bf16x8 b2frag[2][4];
    const bf16x8* wf2 = (const bf16x8*)w2frag_l;
#pragma unroll
    for (int s = 0; s < 2; s++)
#pragma unroll
        for (int nt = 0; nt < 4; nt++) b2frag[s][nt] = wf2[(s * 4 + nt) * 64 + lane];

    f32x4 acc2[2][4];
#pragma unroll
    for (int rt = 0; rt < 2; rt++)
#pragma unroll
        for (int nt = 0; nt < 4; nt++) acc2[rt][nt] = (f32x4)(0.f);

#pragma unroll
    for (int rt = 0; rt < 2; rt++) {
        int rloc = wave * 32 + rt * 16 + l16;
#pragma unroll
        for (int s = 0; s < 2; s++) {
            int k0 = s * 32 + quad * 8;
            bf16x8 tv = *(const bf16x8*)&tl[swz_idx(rloc, k0)];
            bf16x8 a;
#pragma unroll
            for (int i = 0; i < 8; i++) {
                float y = (float)tv[i] * cf[k0 + i] + cf[64 + k0 + i];
                a[i] = (bf16_t)fmaxf(y, 0.f);
            }
#pragma unroll
            for (int nt = 0; nt < 4; nt++)
                acc2[rt][nt] = __builtin_amdgcn_mfma_f32_16x16x32_bf16(
                    a, b2frag[s][nt], acc2[rt][nt], 0, 0, 0);
        }
    }

    // BN2 stats from register-resident h2
#pragma unroll
    for (int nt = 0; nt < 4; nt++) {
        int col = nt * 16 + l16;
        float bias = b2_l[col];
        float s1 = 0.f, s2 = 0.f;
#pragma unroll
        for (int rt = 0; rt < 2; rt++)
#pragma unroll
            for (int r = 0; r < 4; r++) {
                int n = r0 + wave * 32 + rt * 16 + quad * 4 + r;
                if (n < N_NODES) {
                    float v = acc2[rt][nt][r] + bias;
                    s1 += v; s2 += v * v;
                }
            }
        s1 += __shfl_xor(s1, 16); s1 += __shfl_xor(s1, 32);
        s2 += __shfl_xor(s2, 16); s2 += __shfl_xor(s2, 32);
        if (quad == 0) { atomicAdd(&sred[col], s1); atomicAdd(&sred[64 + col], s2); }
    }
    __syncthreads();
    if (tid < 128) atomicAdd(&stats2[tid], sred[tid]);
    gbar(bar, 2 * NBLK_MLP);

    // ---- phase 3: BN2 coefs, h2 -> LDS transpose -> coalesced stores ----
    if (tid < 64) {
        float sa = __hip_atomic_load(stats2 + tid, __ATOMIC_RELAXED, __HIP_MEMORY_SCOPE_AGENT);
        float sb = __hip_atomic_load(stats2 + 64 + tid, __ATOMIC_RELAXED, __HIP_MEMORY_SCOPE_AGENT);
        float mean = sa / (float)N_NODES;
        float var = sb / (float)N_NODES - mean * mean;
        float a = g2[tid] * rsqrtf(var + EPS_BN);
        cf[tid] = a;
        cf[64 + tid] = bb2[tid] - mean * a;
    }
    __syncthreads();   // phase-2 LDS reads done (gbar) ; reuse sbuf as fls
#pragma unroll
    for (int nt = 0; nt < 4; nt++) {
        int col = nt * 16 + l16;
        float bias = b2_l[col];
#pragma unroll
        for (int rt = 0; rt < 2; rt++)
#pragma unroll
            for (int r = 0; r < 4; r++)
                fls[wave * 32 + rt * 16 + quad * 4 + r][col] = acc2[rt][nt][r] + bias;
    }
    __syncthreads();
#pragma unroll
    for (int pass = 0; pass < 4; pass++) {
        int rloc = pass * 32 + (tid >> 3);
        int n = r0 + rloc;
        if (n >= N_NODES) continue;
        int c0 = (tid & 7) * 8;
        f32x4 v0 = *(const f32x4*)&fls[rloc][c0];
        f32x4 v1 = *(const f32x4*)&fls[rloc][c0 + 4];
        f32x4 y0, y1;
#pragma unroll
        for (int k = 0; k < 4; k++) {
            y0[k] = v0[k] * cf[c0 + k] + cf[64 + c0 + k];
            y1[k] = v1[k] * cf[c0 + 4 + k] + cf[64 + c0 + 4 + k];
        }
        if (LAST) {
            *(f32x4*)(out + (size_t)n * 64 + c0) = y0;
            *(f32x4*)(out + (size_t)n * 64 + c0 + 4) = y1;
        } else {
            bf16x8 o;
#pragma unroll
            for (int k = 0; k < 4; k++) {
                y0[k] = fmaxf(y0[k], 0.f);
                y1[k] = fmaxf(y1[k], 0.f);
                o[k] = (bf16_t)y0[k]; o[k + 4] = (bf16_t)y1[k];
            }
            *(f32x4*)(hout + (size_t)n * 64 + c0) = y0;
            *(f32x4*)(hout + (size_t)n * 64 + c0 + 4) = y1;
            *(bf16x8*)(x_bf + (size_t)n * 64 + c0) = o;
        }
    }
}

// ---------------- host ----------------

extern "C" void kernel_launch(void* const* d_in, const int* in_sizes, int n_in,
                              void* d_out, int out_size, void* d_ws, size_t ws_size,
                              hipStream_t stream) {
    const float* x_in   = (const float*)d_in[0];
    const float* pe     = (const float*)d_in[1];
    const float* Lam    = (const float*)d_in[2];
    const float* eattr  = (const float*)d_in[3];
    const float* phi_w1 = (const float*)d_in[4];
    const float* phi_b1 = (const float*)d_in[5];
    const float* phi_w2 = (const float*)d_in[6];
    const float* phi_b2 = (const float*)d_in[7];
    const float* enc_w  = (const float*)d_in[8];
    const float* enc_b  = (const float*)d_in[9];
    const float* lin_w  = (const float*)d_in[10];
    const float* lin_b  = (const float*)d_in[11];
    const float* mlp_w1 = (const float*)d_in[12];
    const float* mlp_b1 = (const float*)d_in[13];
    const float* bn1_g  = (const float*)d_in[14];
    const float* bn1_b  = (const float*)d_in[15];
    const float* mlp_w2 = (const float*)d_in[16];
    const float* mlp_b2 = (const float*)d_in[17];
    const float* bn2_g  = (const float*)d_in[18];
    const float* bn2_b  = (const float*)d_in[19];
    const int* edge_index = (const int*)d_in[20];
    const int* batch      = (const int*)d_in[21];
    float* out = (float*)d_out;

    char* ws = (char*)d_ws;
    size_t off = 0;
    auto alloc = [&](size_t bytes) -> void* {
        void* p = ws + off;
        off += (bytes + 255) & ~(size_t)255;
        return p;
    };
    bf16_t* feat      = (bf16_t*)alloc((size_t)N_EDGES * 128 * 2);
    int4* edat        = (int4*)alloc((size_t)N_EDGES * 16);
    int* row_ptr      = (int*)alloc((size_t)(N_NODES + 1) * 4);
    int* blk          = (int*)alloc(128 * 4);
    // zero-init region (one memset): counts | cursor | stats | bar
    int* counts       = (int*)alloc((size_t)N_NODES * 4);
    int* cursor       = (int*)alloc((size_t)N_NODES * 4);
    float* stats      = (float*)alloc((size_t)NL * 256 * 4);
    int* bar          = (int*)alloc((size_t)NL * 4);
    size_t zbytes     = (char*)(bar + NL) - (char*)counts;
    float* h          = (float*)alloc((size_t)N_NODES * 64 * 4);
    bf16_t* x_bf      = (bf16_t*)alloc((size_t)N_NODES * 64 * 2);
    bf16_t* w_all     = (bf16_t*)alloc((size_t)NL * NB * QM * 2);
    bf16_t* wcat_frag = (bf16_t*)alloc((size_t)NL * 8192 * 2);
    bf16_t* w1frag    = (bf16_t*)alloc((size_t)NL * 4096 * 2);
    bf16_t* w2frag    = (bf16_t*)alloc((size_t)NL * 4096 * 2);
    float* cvec       = (float*)alloc((size_t)NL * 64 * 4);

    // ---- one-time setup ----
    hipMemsetAsync(counts, 0, zbytes, stream);
    k_count<<<3125, 256, 0, stream>>>(edge_index + N_EDGES, counts);
    k_scan1<<<98, 1024, 0, stream>>>(counts, row_ptr, blk);
    k_scan2<<<1, 128, 0, stream>>>(blk);
    k_scan3<<<98, 1024, 0, stream>>>(blk, row_ptr);
    k_scatter<<<3125, 256, 0, stream>>>(edge_index, batch, row_ptr, cursor, edat);
    k_permute<<<25000, 256, 0, stream>>>(pe, eattr, edat, feat);
    k_phi<<<50, 256, 0, stream>>>(Lam, phi_w1, phi_b1, phi_w2, phi_b2, w_all);
    k_prep<<<NL, 256, 0, stream>>>(enc_w, enc_b, lin_w, lin_b, mlp_w1, mlp_w2,
                                   wcat_frag, w1frag, w2frag, cvec);

    // ---- layers ----
    k_hinit0<<<3125, 256, 0, stream>>>(x_in, pe, x_bf, h, out + (size_t)N_NODES * 64);
    for (int l = 0; l < NL; l++) {
        float* s1 = stats + l * 256;
        float* s2 = stats + l * 256 + 128;
        k_edge<<<6250, 256, 0, stream>>>(feat, edat, row_ptr,
                                         w_all + (size_t)l * NB * QM,
                                         wcat_frag + (size_t)l * 8192,
                                         cvec + (size_t)l * 64, x_bf, h);
        if (l < NL - 1)
            k_mlp<0><<<NBLK_MLP, 256, 0, stream>>>(
                h, w1frag + (size_t)l * 4096, w2frag + (size_t)l * 4096,
                mlp_b1 + l * 64, bn1_g + l * 64, bn1_b + l * 64,
                mlp_b2 + l * 64, bn2_g + l * 64, bn2_b + l * 64,
                s1, s2, bar + l, h, x_bf, (float*)nullptr);
        else
            k_mlp<1><<<NBLK_MLP, 256, 0, stream>>>(
                h, w1frag + (size_t)l * 4096, w2frag + (size_t)l * 4096,
                mlp_b1 + l * 64, bn1_g + l * 64, bn1_b + l * 64,
                mlp_b2 + l * 64, bn2_g + l * 64, bn2_b + l * 64,
                s1, s2, bar + l, h, x_bf, out);
    }
}

// Round 8
// 1098.103 us; speedup vs baseline: 1.1705x; 1.1705x over previous
//
#include <hip/hip_runtime.h>

#define N_NODES 100000
#define N_EDGES 800000
#define NB 100
#define NL 4
#define QM 32
#define EPS_BN 1e-5f
#define NTILE 782      // ceil(N_NODES / 128)
#define NBLK_MLP 512   // 2 tiles/block, exactly 2 blocks/CU -> balanced grid barrier

typedef __bf16 bf16_t;
typedef __bf16 bf16x8 __attribute__((ext_vector_type(8)));
typedef __bf16 bf16x4 __attribute__((ext_vector_type(4)));
typedef __bf16 bf16x2 __attribute__((ext_vector_type(2)));
typedef float f32x4 __attribute__((ext_vector_type(4)));

// ---------------- setup: counting sort by dst ----------------

__global__ void k_count(const int* __restrict__ dst, int* __restrict__ counts) {
    int e = blockIdx.x * 256 + threadIdx.x;
    if (e < N_EDGES) atomicAdd(&counts[dst[e]], 1);
}

__global__ void k_scan1(const int* __restrict__ counts, int* __restrict__ row_ptr,
                        int* __restrict__ blk) {
    __shared__ int s[1024];
    int i = blockIdx.x * 1024 + threadIdx.x;
    int v = (i < N_NODES) ? counts[i] : 0;
    s[threadIdx.x] = v;
    __syncthreads();
    for (int off = 1; off < 1024; off <<= 1) {
        int u = (threadIdx.x >= off) ? s[threadIdx.x - off] : 0;
        __syncthreads();
        s[threadIdx.x] += u;
        __syncthreads();
    }
    if (i < N_NODES) row_ptr[i] = s[threadIdx.x] - v;   // block-local exclusive
    if (threadIdx.x == 1023) blk[blockIdx.x] = s[1023]; // block total
}

__global__ void k_scan2(int* __restrict__ blk) { // exclusive scan of 98 block totals
    __shared__ int s[128];
    int t = threadIdx.x;
    int v = (t < 98) ? blk[t] : 0;
    s[t] = v;
    __syncthreads();
    for (int off = 1; off < 128; off <<= 1) {
        int u = (t >= off) ? s[t - off] : 0;
        __syncthreads();
        s[t] += u;
        __syncthreads();
    }
    if (t < 98) blk[t] = s[t] - v;
}

__global__ void k_scan3(const int* __restrict__ blk, int* __restrict__ row_ptr) {
    int i = blockIdx.x * 1024 + threadIdx.x;
    if (i < N_NODES) row_ptr[i] += blk[blockIdx.x];
    if (i == 0) row_ptr[N_NODES] = N_EDGES;
}

// one scattered 16B write per edge: edat[pos] = {src, dst, graph, orig_e}
__global__ void k_scatter(const int* __restrict__ ei, const int* __restrict__ batch,
                          const int* __restrict__ row_ptr, int* __restrict__ cursor,
                          int4* __restrict__ edat) {
    int e = blockIdx.x * 256 + threadIdx.x;
    if (e >= N_EDGES) return;
    int s = ei[e], d = ei[N_EDGES + e];
    int pos = row_ptr[d] + atomicAdd(&cursor[d], 1);
    edat[pos] = make_int4(s, d, batch[s], e);
}

// gather-style: indexed by sorted slot p (coalesced writes), gathered reads.
// feat[p] = [z_re(32) | z_im(32) | ea(64)] bf16. 16 lanes per edge, 2 edges per
// group for doubled memory-level parallelism (all 6 gathers in flight at once).
__global__ void k_permute(const float* __restrict__ pe, const float* __restrict__ ea,
                          const int4* __restrict__ edat, bf16_t* __restrict__ feat) {
    int t = blockIdx.x * 256 + threadIdx.x;
    int g = t >> 4, k = t & 15;
    size_t p0 = (size_t)g << 1;
    int4 ed0 = edat[p0];
    int4 ed1 = edat[p0 + 1];
    f32x4 s0 = *(const f32x4*)(pe + (size_t)ed0.x * 64 + k * 4);
    f32x4 d0 = *(const f32x4*)(pe + (size_t)ed0.y * 64 + k * 4);
    f32x4 a0 = *(const f32x4*)(ea + (size_t)ed0.w * 64 + k * 4);
    f32x4 s1 = *(const f32x4*)(pe + (size_t)ed1.x * 64 + k * 4);
    f32x4 d1 = *(const f32x4*)(pe + (size_t)ed1.y * 64 + k * 4);
    f32x4 a1 = *(const f32x4*)(ea + (size_t)ed1.w * 64 + k * 4);

    bf16x4 ao0, ao1;
#pragma unroll
    for (int i = 0; i < 4; i++) { ao0[i] = (bf16_t)a0[i]; ao1[i] = (bf16_t)a1[i]; }
    bf16x2 re0, im0, re1, im1;
    re0[0] = (bf16_t)(s0[0] * d0[0] + s0[1] * d0[1]);
    re0[1] = (bf16_t)(s0[2] * d0[2] + s0[3] * d0[3]);
    im0[0] = (bf16_t)(s0[1] * d0[0] - s0[0] * d0[1]);
    im0[1] = (bf16_t)(s0[3] * d0[2] - s0[2] * d0[3]);
    re1[0] = (bf16_t)(s1[0] * d1[0] + s1[1] * d1[1]);
    re1[1] = (bf16_t)(s1[2] * d1[2] + s1[3] * d1[3]);
    im1[0] = (bf16_t)(s1[1] * d1[0] - s1[0] * d1[1]);
    im1[1] = (bf16_t)(s1[3] * d1[2] - s1[2] * d1[3]);

    bf16_t* f0 = feat + p0 * 128;
    *(bf16x2*)(f0 + 2 * k) = re0;
    *(bf16x2*)(f0 + 32 + 2 * k) = im0;
    *(bf16x4*)(f0 + 64 + 4 * k) = ao0;
    bf16_t* f1 = f0 + 128;
    *(bf16x2*)(f1 + 2 * k) = re1;
    *(bf16x2*)(f1 + 32 + 2 * k) = im1;
    *(bf16x4*)(f1 + 64 + 4 * k) = ao1;
}

// ---------------- weight prep ----------------

__global__ void k_phi(const float* __restrict__ Lam, const float* __restrict__ w1,
                      const float* __restrict__ b1, const float* __restrict__ w2,
                      const float* __restrict__ b2, bf16_t* __restrict__ w_all) {
    int idx = blockIdx.x * 256 + threadIdx.x;
    if (idx >= NL * NB * QM) return;
    int l = idx / (NB * QM);
    int rem = idx % (NB * QM);
    float lam = Lam[rem];
    float acc = b2[l];
    for (int i = 0; i < 16; i++) {
        float h = lam * w1[l * 16 + i] + b1[l * 16 + i];
        acc += fmaxf(h, 0.f) * w2[l * 16 + i];
    }
    w_all[idx] = (bf16_t)acc;
}

__global__ void k_prep(const float* __restrict__ enc_w, const float* __restrict__ enc_b,
                       const float* __restrict__ lin_w, const float* __restrict__ lin_b,
                       const float* __restrict__ mlp_w1, const float* __restrict__ mlp_w2,
                       bf16_t* __restrict__ wcat_frag, bf16_t* __restrict__ w1frag,
                       bf16_t* __restrict__ w2frag, float* __restrict__ cvec) {
    __shared__ float lds[128][64];
    int l = blockIdx.x, tid = threadIdx.x;
    const float* ew = enc_w + l * 64 * 64;
    const float* lw = lin_w + l * 64 * 64;
    for (int idx = tid; idx < 64 * 64; idx += 256) {
        int r = idx >> 6, c = idx & 63;
        float acc = 0.f;
        for (int k = 0; k < 64; k++) acc += ew[r * 64 + k] * lw[k * 64 + c];
        lds[r][c] = acc;
        lds[64 + r][c] = lw[r * 64 + c];
    }
    if (tid < 64) {
        float acc = lin_b[l * 64 + tid];
        for (int k = 0; k < 64; k++) acc += enc_b[l * 64 + k] * lw[k * 64 + tid];
        cvec[l * 64 + tid] = acc;
    }
    __syncthreads();
    for (int idx = tid; idx < 16 * 512; idx += 256) {
        int sn = idx >> 9, lane = (idx >> 3) & 63, j = idx & 7;
        int s = sn >> 2, nt = sn & 3;
        int row = 32 * s + (lane >> 4) * 8 + j;
        int col = 16 * nt + (lane & 15);
        wcat_frag[l * 8192 + idx] = (bf16_t)lds[row][col];
    }
    for (int idx = tid; idx < 8 * 512; idx += 256) {
        int sn = idx >> 9, lane = (idx >> 3) & 63, j = idx & 7;
        int s = sn >> 2, nt = sn & 3;
        int row = 32 * s + (lane >> 4) * 8 + j; // k index
        int col = 16 * nt + (lane & 15);
        w1frag[l * 4096 + idx] = (bf16_t)mlp_w1[(l * 64 + row) * 64 + col];
        w2frag[l * 4096 + idx] = (bf16_t)mlp_w2[(l * 64 + row) * 64 + col];
    }
}

// ---------------- per-layer kernels ----------------

// layer 0 init: x_bf = bf16(x), h = x; also pe passthrough to out (replaces memcpy)
__global__ void k_hinit0(const float* __restrict__ x, const float* __restrict__ pe,
                         bf16_t* __restrict__ x_bf, float* __restrict__ h,
                         float* __restrict__ out_pe) {
    size_t i = ((size_t)blockIdx.x * 256 + threadIdx.x) * 8;
    f32x4 a = *(const f32x4*)(x + i), b = *(const f32x4*)(x + i + 4);
    *(f32x4*)(h + i) = a;
    *(f32x4*)(h + i + 4) = b;
    bf16x8 o;
#pragma unroll
    for (int k = 0; k < 4; k++) { o[k] = (bf16_t)a[k]; o[k + 4] = (bf16_t)b[k]; }
    *(bf16x8*)(x_bf + i) = o;
    f32x4 p0 = *(const f32x4*)(pe + i), p1 = *(const f32x4*)(pe + i + 4);
    *(f32x4*)(out_pe + i) = p0;
    *(f32x4*)(out_pe + i + 4) = p1;
}

// 128 dst-sorted edges per block: msg = relu(x[src] + feat @ Wcat + cvec),
// then in-block segment sum into h (h pre-initialized to x).
__global__ void k_edge(const bf16_t* __restrict__ feat, const int4* __restrict__ edat,
                       const int* __restrict__ row_ptr, const bf16_t* __restrict__ w_l,
                       const bf16_t* __restrict__ wcat_l, const float* __restrict__ cvec_l,
                       const bf16_t* __restrict__ x_bf, float* __restrict__ h) {
    __shared__ float msg[128][68];
    int tid = threadIdx.x;
    int wave = tid >> 6, lane = tid & 63;
    int quad = lane >> 4, l16 = lane & 15;
    int e0 = blockIdx.x * 128;

    bf16x8 bfrag[4][4];
    const bf16x8* wf = (const bf16x8*)wcat_l;
#pragma unroll
    for (int s = 0; s < 4; s++)
#pragma unroll
        for (int nt = 0; nt < 4; nt++) bfrag[s][nt] = wf[(s * 4 + nt) * 64 + lane];

    f32x4 acc[2][4];
#pragma unroll
    for (int rt = 0; rt < 2; rt++)
#pragma unroll
        for (int nt = 0; nt < 4; nt++) acc[rt][nt] = (f32x4)(0.f);

    int em[2];
    bf16x8 wch[2];
#pragma unroll
    for (int rt = 0; rt < 2; rt++) {
        em[rt] = e0 + wave * 32 + rt * 16 + l16;
        int eg = edat[em[rt]].z;
        wch[rt] = *(const bf16x8*)(w_l + (size_t)eg * QM + quad * 8);
    }
#pragma unroll
    for (int s = 0; s < 4; s++) {
        bf16x8 afr[2];
#pragma unroll
        for (int rt = 0; rt < 2; rt++) {
            bf16x8 v = *(const bf16x8*)(feat + (size_t)em[rt] * 128 + s * 32 + quad * 8);
            if (s < 2) {
                bf16x8 a;
#pragma unroll
                for (int i = 0; i < 8; i++) a[i] = (bf16_t)((float)v[i] * (float)wch[rt][i]);
                afr[rt] = a;
            } else {
                afr[rt] = v;
            }
        }
#pragma unroll
        for (int rt = 0; rt < 2; rt++)
#pragma unroll
            for (int nt = 0; nt < 4; nt++)
                acc[rt][nt] = __builtin_amdgcn_mfma_f32_16x16x32_bf16(afr[rt], bfrag[s][nt],
                                                                     acc[rt][nt], 0, 0, 0);
    }
    // C layout: row = quad*4 + r, col = lane&15 (per 16x16 tile)
#pragma unroll
    for (int nt = 0; nt < 4; nt++) {
        float cv = cvec_l[nt * 16 + l16];
#pragma unroll
        for (int rt = 0; rt < 2; rt++)
#pragma unroll
            for (int r = 0; r < 4; r++)
                msg[wave * 32 + rt * 16 + quad * 4 + r][nt * 16 + l16] = acc[rt][nt][r] + cv;
    }
    __syncthreads();
    // add x[src] (bf16 row = 128B per 8-lane group), relu
#pragma unroll
    for (int it = 0; it < 4; it++) {
        int j = it * 32 + (tid >> 3);
        int l8 = tid & 7;
        int srcn = edat[e0 + j].x;
        bf16x8 xv = *(const bf16x8*)(x_bf + (size_t)srcn * 64 + l8 * 8);
        float* mrow = &msg[j][l8 * 8];
        f32x4 m0 = *(const f32x4*)mrow, m1 = *(const f32x4*)(mrow + 4);
#pragma unroll
        for (int k = 0; k < 4; k++) {
            m0[k] = fmaxf(m0[k] + (float)xv[k], 0.f);
            m1[k] = fmaxf(m1[k] + (float)xv[k + 4], 0.f);
        }
        *(f32x4*)mrow = m0;
        *(f32x4*)(mrow + 4) = m1;
    }
    __syncthreads();
    // segment reduce over this block's edge window
    int nfirst = edat[e0].y, nlast = edat[e0 + 127].y;
    int c = tid & 63;
    for (int n = nfirst + (tid >> 6); n <= nlast; n += 4) {
        int rs = row_ptr[n], re = row_ptr[n + 1];
        int a = rs > e0 ? rs : e0;
        int b = re < e0 + 128 ? re : e0 + 128;
        if (a >= b) continue;
        float sum = 0.f;
        for (int jj = a; jj < b; jj++) sum += msg[jj - e0][c];
        float* addr = h + (size_t)n * 64 + c;
        if (rs >= e0 && re <= e0 + 128) *addr += sum;  // sole owner
        else atomicAdd(addr, sum);                     // boundary node
    }
}

// ---- fused MLP: t = h@w1+b1 -> BN1 -> relu -> @w2+b2 -> BN2 [-> relu] ----
// One kernel, two grid barriers. R5 config (512 blocks, 2 tiles, 2 blocks/CU:
// uniform load across CUs -- R7 showed non-multiple-of-256 grids straggle at
// the barrier). This round's experiment: SHARD the contended atomics x8.
// stats1/stats2 are 8 shadow copies (block adds into shard bid&7 -> 64-way
// instead of 512-way serialization per address); the barrier is 8 counters on
// separate 128B lines, spinners poll the sum. All cross-block data still flows
// through agent-scope atomics (coherent); RELEASE arrive + RELAXED spin only.

__device__ __forceinline__ int swz_idx(int row, int col) {
    // bf16 element index with byte-XOR swizzle; keeps 16B alignment for b128 ops
    return ((row * 128 + col * 2) ^ ((row & 7) << 4)) >> 1;
}

__device__ __forceinline__ void gbar(int* bars, int target) {
    __syncthreads();
    if (threadIdx.x == 0) {
        __hip_atomic_fetch_add(bars + (blockIdx.x & 7) * 32, 1,
                               __ATOMIC_RELEASE, __HIP_MEMORY_SCOPE_AGENT);
        int s;
        do {
            s = 0;
#pragma unroll
            for (int j = 0; j < 8; j++)
                s += __hip_atomic_load(bars + j * 32, __ATOMIC_RELAXED,
                                       __HIP_MEMORY_SCOPE_AGENT);
            if (s < target) __builtin_amdgcn_s_sleep(16);
        } while (s < target);
    }
    __syncthreads();
}

template <int LAST>
__global__ __launch_bounds__(256, 2) void k_mlp(
    const float* __restrict__ h, const bf16_t* __restrict__ w1frag_l,
    const bf16_t* __restrict__ w2frag_l, const float* __restrict__ b1_l,
    const float* __restrict__ g1, const float* __restrict__ bb1,
    const float* __restrict__ b2_l, const float* __restrict__ g2,
    const float* __restrict__ bb2, float* __restrict__ stats1,
    float* __restrict__ stats2, int* __restrict__ bars, float* __restrict__ hout,
    bf16_t* __restrict__ x_bf, float* __restrict__ out) {
    // sbuf: phases 1-2 = two 128x64 bf16 t-tiles (swizzled);
    // phase 3 = one [128][68] f32 tile (h2 transpose for coalesced stores).
    __shared__ __align__(16) char sbuf[34816];
    __shared__ float sred[128];
    __shared__ float cf[128];
    bf16_t* tls0 = (bf16_t*)sbuf;
    bf16_t* tls1 = (bf16_t*)(sbuf + 16384);
    float (*fls)[68] = (float(*)[68])sbuf;
    int tid = threadIdx.x, wave = tid >> 6, lane = tid & 63, quad = lane >> 4, l16 = lane & 15;
    int shard = (blockIdx.x & 7) * 128;

    bf16x8 bfrag[2][4];
    const bf16x8* wf1 = (const bf16x8*)w1frag_l;
#pragma unroll
    for (int s = 0; s < 2; s++)
#pragma unroll
        for (int nt = 0; nt < 4; nt++) bfrag[s][nt] = wf1[(s * 4 + nt) * 64 + lane];

    if (tid < 128) sred[tid] = 0.f;
    __syncthreads();

    // ---- phase 1: t-tiles + BN1 stats ----
#pragma unroll
    for (int ti = 0; ti < 2; ti++) {
        int tile = blockIdx.x + ti * NBLK_MLP;
        if (tile >= NTILE) continue;
        bf16_t* tl = ti ? tls1 : tls0;
        int r0 = tile * 128;
        f32x4 acc[2][4];
#pragma unroll
        for (int rt = 0; rt < 2; rt++)
#pragma unroll
            for (int nt = 0; nt < 4; nt++) acc[rt][nt] = (f32x4)(0.f);
#pragma unroll
        for (int rt = 0; rt < 2; rt++) {
            int n = r0 + wave * 32 + rt * 16 + l16;
            bool valid = n < N_NODES;
#pragma unroll
            for (int s = 0; s < 2; s++) {
                bf16x8 a;
                if (valid) {
                    const float* hp = h + (size_t)n * 64 + s * 32 + quad * 8;
                    f32x4 v0 = *(const f32x4*)hp, v1 = *(const f32x4*)(hp + 4);
#pragma unroll
                    for (int i = 0; i < 4; i++) { a[i] = (bf16_t)v0[i]; a[i + 4] = (bf16_t)v1[i]; }
                } else {
#pragma unroll
                    for (int i = 0; i < 8; i++) a[i] = (bf16_t)0.f;
                }
#pragma unroll
                for (int nt = 0; nt < 4; nt++)
                    acc[rt][nt] = __builtin_amdgcn_mfma_f32_16x16x32_bf16(a, bfrag[s][nt],
                                                                         acc[rt][nt], 0, 0, 0);
            }
        }
#pragma unroll
        for (int nt = 0; nt < 4; nt++) {
            int col = nt * 16 + l16;
            float bias = b1_l[col];
            float s1 = 0.f, s2 = 0.f;
#pragma unroll
            for (int rt = 0; rt < 2; rt++)
#pragma unroll
                for (int r = 0; r < 4; r++) {
                    int rloc = wave * 32 + rt * 16 + quad * 4 + r;
                    int n = r0 + rloc;
                    if (n < N_NODES) {
                        float v = acc[rt][nt][r] + bias;
                        tl[swz_idx(rloc, col)] = (bf16_t)v;
                        s1 += v; s2 += v * v;
                    } else {
                        tl[swz_idx(rloc, col)] = (bf16_t)0.f;
                    }
                }
            s1 += __shfl_xor(s1, 16); s1 += __shfl_xor(s1, 32);
            s2 += __shfl_xor(s2, 16); s2 += __shfl_xor(s2, 32);
            if (quad == 0) { atomicAdd(&sred[col], s1); atomicAdd(&sred[64 + col], s2); }
        }
    }
    __syncthreads();
    if (tid < 128) atomicAdd(&stats1[shard + tid], sred[tid]);
    gbar(bars, NBLK_MLP);

    // ---- phase 2: BN1 coefs (sum 8 shards), second GEMM (h2 in registers) ----
    if (tid < 128) sred[tid] = 0.f;
    if (tid < 64) {
        float sa = 0.f, sb = 0.f;
#pragma unroll
        for (int j = 0; j < 8; j++) {
            sa += __hip_atomic_load(stats1 + j * 128 + tid, __ATOMIC_RELAXED,
                                    __HIP_MEMORY_SCOPE_AGENT);
            sb += __hip_atomic_load(stats1 + j * 128 + 64 + tid, __ATOMIC_RELAXED,
                                    __HIP_MEMORY_SCOPE_AGENT);
        }
        float mean = sa / (float)N_NODES;
        float var = sb / (float)N_NODES - mean * mean;
        float a = g1[tid] * rsqrtf(var + EPS_BN);
        cf[tid] = a;
        cf[64 + tid] = bb1[tid] - mean * a;
    }
    __syncthreads();

    bf16x8 b2frag[2][4];
    const bf16x8* wf2 = (const bf16x8*)w2frag_l;
#pragma unroll
    for (int s = 0; s < 2; s++)
#pragma unroll
        for (int nt = 0; nt < 4; nt++) b2frag[s][nt] = wf2[(s * 4 + nt) * 64 + lane];

    f32x4 acc2[2][2][4];
#pragma unroll
    for (int ti = 0; ti < 2; ti++)
#pragma unroll
        for (int rt = 0; rt < 2; rt++)
#pragma unroll
            for (int nt = 0; nt < 4; nt++) acc2[ti][rt][nt] = (f32x4)(0.f);

#pragma unroll
    for (int ti = 0; ti < 2; ti++) {
        int tile = blockIdx.x + ti * NBLK_MLP;
        if (tile >= NTILE) continue;
        bf16_t* tl = ti ? tls1 : tls0;
#pragma unroll
        for (int rt = 0; rt < 2; rt++) {
            int rloc = wave * 32 + rt * 16 + l16;
#pragma unroll
            for (int s = 0; s < 2; s++) {
                int k0 = s * 32 + quad * 8;
                bf16x8 tv = *(const bf16x8*)&tl[swz_idx(rloc, k0)];
                bf16x8 a;
#pragma unroll
                for (int i = 0; i < 8; i++) {
                    float y = (float)tv[i] * cf[k0 + i] + cf[64 + k0 + i];
                    a[i] = (bf16_t)fmaxf(y, 0.f);
                }
#pragma unroll
                for (int nt = 0; nt < 4; nt++)
                    acc2[ti][rt][nt] = __builtin_amdgcn_mfma_f32_16x16x32_bf16(
                        a, b2frag[s][nt], acc2[ti][rt][nt], 0, 0, 0);
            }
        }
    }

    // BN2 stats from register-resident h2
#pragma unroll
    for (int nt = 0; nt < 4; nt++) {
        int col = nt * 16 + l16;
        float bias = b2_l[col];
        float s1 = 0.f, s2 = 0.f;
#pragma unroll
        for (int ti = 0; ti < 2; ti++) {
            int tile = blockIdx.x + ti * NBLK_MLP;
            if (tile >= NTILE) continue;
            int r0 = tile * 128;
#pragma unroll
            for (int rt = 0; rt < 2; rt++)
#pragma unroll
                for (int r = 0; r < 4; r++) {
                    int n = r0 + wave * 32 + rt * 16 + quad * 4 + r;
                    if (n < N_NODES) {
                        float v = acc2[ti][rt][nt][r] + bias;
                        s1 += v; s2 += v * v;
                    }
                }
        }
        s1 += __shfl_xor(s1, 16); s1 += __shfl_xor(s1, 32);
        s2 += __shfl_xor(s2, 16); s2 += __shfl_xor(s2, 32);
        if (quad == 0) { atomicAdd(&sred[col], s1); atomicAdd(&sred[64 + col], s2); }
    }
    __syncthreads();
    if (tid < 128) atomicAdd(&stats2[shard + tid], sred[tid]);
    gbar(bars, 2 * NBLK_MLP);

    // ---- phase 3: BN2 coefs (sum 8 shards), h2 -> LDS -> coalesced stores ----
    if (tid < 64) {
        float sa = 0.f, sb = 0.f;
#pragma unroll
        for (int j = 0; j < 8; j++) {
            sa += __hip_atomic_load(stats2 + j * 128 + tid, __ATOMIC_RELAXED,
                                    __HIP_MEMORY_SCOPE_AGENT);
            sb += __hip_atomic_load(stats2 + j * 128 + 64 + tid, __ATOMIC_RELAXED,
                                    __HIP_MEMORY_SCOPE_AGENT);
        }
        float mean = sa / (float)N_NODES;
        float var = sb / (float)N_NODES - mean * mean;
        float a = g2[tid] * rsqrtf(var + EPS_BN);
        cf[tid] = a;
        cf[64 + tid] = bb2[tid] - mean * a;
    }
#pragma unroll
    for (int ti = 0; ti < 2; ti++) {
        int tile = blockIdx.x + ti * NBLK_MLP;
        if (tile >= NTILE) continue;   // block-uniform: all threads agree
        __syncthreads();               // fls free (tls dead / prev tile done); cf visible
        int r0 = tile * 128;
#pragma unroll
        for (int nt = 0; nt < 4; nt++) {
            int col = nt * 16 + l16;
            float bias = b2_l[col];
#pragma unroll
            for (int rt = 0; rt < 2; rt++)
#pragma unroll
                for (int r = 0; r < 4; r++)
                    fls[wave * 32 + rt * 16 + quad * 4 + r][col] = acc2[ti][rt][nt][r] + bias;
        }
        __syncthreads();
#pragma unroll
        for (int pass = 0; pass < 4; pass++) {
            int rloc = pass * 32 + (tid >> 3);
            int n = r0 + rloc;
            if (n >= N_NODES) continue;
            int c0 = (tid & 7) * 8;
            f32x4 v0 = *(const f32x4*)&fls[rloc][c0];
            f32x4 v1 = *(const f32x4*)&fls[rloc][c0 + 4];
            f32x4 y0, y1;
#pragma unroll
            for (int k = 0; k < 4; k++) {
                y0[k] = v0[k] * cf[c0 + k] + cf[64 + c0 + k];
                y1[k] = v1[k] * cf[c0 + 4 + k] + cf[64 + c0 + 4 + k];
            }
            if (LAST) {
                *(f32x4*)(out + (size_t)n * 64 + c0) = y0;
                *(f32x4*)(out + (size_t)n * 64 + c0 + 4) = y1;
            } else {
                bf16x8 o;
#pragma unroll
                for (int k = 0; k < 4; k++) {
                    y0[k] = fmaxf(y0[k], 0.f);
                    y1[k] = fmaxf(y1[k], 0.f);
                    o[k] = (bf16_t)y0[k]; o[k + 4] = (bf16_t)y1[k];
                }
                *(f32x4*)(hout + (size_t)n * 64 + c0) = y0;
                *(f32x4*)(hout + (size_t)n * 64 + c0 + 4) = y1;
                *(bf16x8*)(x_bf + (size_t)n * 64 + c0) = o;
            }
        }
    }
}

// ---------------- host ----------------

extern "C" void kernel_launch(void* const* d_in, const int* in_sizes, int n_in,
                              void* d_out, int out_size, void* d_ws, size_t ws_size,
                              hipStream_t stream) {
    const float* x_in   = (const float*)d_in[0];
    const float* pe     = (const float*)d_in[1];
    const float* Lam    = (const float*)d_in[2];
    const float* eattr  = (const float*)d_in[3];
    const float* phi_w1 = (const float*)d_in[4];
    const float* phi_b1 = (const float*)d_in[5];
    const float* phi_w2 = (const float*)d_in[6];
    const float* phi_b2 = (const float*)d_in[7];
    const float* enc_w  = (const float*)d_in[8];
    const float* enc_b  = (const float*)d_in[9];
    const float* lin_w  = (const float*)d_in[10];
    const float* lin_b  = (const float*)d_in[11];
    const float* mlp_w1 = (const float*)d_in[12];
    const float* mlp_b1 = (const float*)d_in[13];
    const float* bn1_g  = (const float*)d_in[14];
    const float* bn1_b  = (const float*)d_in[15];
    const float* mlp_w2 = (const float*)d_in[16];
    const float* mlp_b2 = (const float*)d_in[17];
    const float* bn2_g  = (const float*)d_in[18];
    const float* bn2_b  = (const float*)d_in[19];
    const int* edge_index = (const int*)d_in[20];
    const int* batch      = (const int*)d_in[21];
    float* out = (float*)d_out;

    char* ws = (char*)d_ws;
    size_t off = 0;
    auto alloc = [&](size_t bytes) -> void* {
        void* p = ws + off;
        off += (bytes + 255) & ~(size_t)255;
        return p;
    };
    bf16_t* feat      = (bf16_t*)alloc((size_t)N_EDGES * 128 * 2);
    int4* edat        = (int4*)alloc((size_t)N_EDGES * 16);
    int* row_ptr      = (int*)alloc((size_t)(N_NODES + 1) * 4);
    int* blk          = (int*)alloc(128 * 4);
    // zero-init region (one memset): counts | cursor | stats(8-shard) | bar(8-shard)
    int* counts       = (int*)alloc((size_t)N_NODES * 4);
    int* cursor       = (int*)alloc((size_t)N_NODES * 4);
    float* stats      = (float*)alloc((size_t)NL * 2048 * 4); // per layer: s1[8][128], s2[8][128]
    int* bar          = (int*)alloc((size_t)NL * 256 * 4);    // per layer: 8 counters, 128B apart
    size_t zbytes     = (char*)(bar + NL * 256) - (char*)counts;
    float* h          = (float*)alloc((size_t)N_NODES * 64 * 4);
    bf16_t* x_bf      = (bf16_t*)alloc((size_t)N_NODES * 64 * 2);
    bf16_t* w_all     = (bf16_t*)alloc((size_t)NL * NB * QM * 2);
    bf16_t* wcat_frag = (bf16_t*)alloc((size_t)NL * 8192 * 2);
    bf16_t* w1frag    = (bf16_t*)alloc((size_t)NL * 4096 * 2);
    bf16_t* w2frag    = (bf16_t*)alloc((size_t)NL * 4096 * 2);
    float* cvec       = (float*)alloc((size_t)NL * 64 * 4);

    // ---- one-time setup ----
    hipMemsetAsync(counts, 0, zbytes, stream);
    k_count<<<3125, 256, 0, stream>>>(edge_index + N_EDGES, counts);
    k_scan1<<<98, 1024, 0, stream>>>(counts, row_ptr, blk);
    k_scan2<<<1, 128, 0, stream>>>(blk);
    k_scan3<<<98, 1024, 0, stream>>>(blk, row_ptr);
    k_scatter<<<3125, 256, 0, stream>>>(edge_index, batch, row_ptr, cursor, edat);
    k_permute<<<25000, 256, 0, stream>>>(pe, eattr, edat, feat);
    k_phi<<<50, 256, 0, stream>>>(Lam, phi_w1, phi_b1, phi_w2, phi_b2, w_all);
    k_prep<<<NL, 256, 0, stream>>>(enc_w, enc_b, lin_w, lin_b, mlp_w1, mlp_w2,
                                   wcat_frag, w1frag, w2frag, cvec);

    // ---- layers ----
    k_hinit0<<<3125, 256, 0, stream>>>(x_in, pe, x_bf, h, out + (size_t)N_NODES * 64);
    for (int l = 0; l < NL; l++) {
        float* s1 = stats + (size_t)l * 2048;
        float* s2 = stats + (size_t)l * 2048 + 1024;
        int* bl = bar + (size_t)l * 256;
        k_edge<<<6250, 256, 0, stream>>>(feat, edat, row_ptr,
                                         w_all + (size_t)l * NB * QM,
                                         wcat_frag + (size_t)l * 8192,
                                         cvec + (size_t)l * 64, x_bf, h);
        if (l < NL - 1)
            k_mlp<0><<<NBLK_MLP, 256, 0, stream>>>(
                h, w1frag + (size_t)l * 4096, w2frag + (size_t)l * 4096,
                mlp_b1 + l * 64, bn1_g + l * 64, bn1_b + l * 64,
                mlp_b2 + l * 64, bn2_g + l * 64, bn2_b + l * 64,
                s1, s2, bl, h, x_bf, (float*)nullptr);
        else
            k_mlp<1><<<NBLK_MLP, 256, 0, stream>>>(
                h, w1frag + (size_t)l * 4096, w2frag + (size_t)l * 4096,
                mlp_b1 + l * 64, bn1_g + l * 64, bn1_b + l * 64,
                mlp_b2 + l * 64, bn2_g + l * 64, bn2_b + l * 64,
                s1, s2, bl, h, x_bf, out);
    }
}

// Round 10
// 1090.002 us; speedup vs baseline: 1.1792x; 1.0074x over previous
//
#include <hip/hip_runtime.h>

#define N_NODES 100000
#define N_EDGES 800000
#define NB 100
#define NL 4
#define QM 32
#define EPS_BN 1e-5f
#define NTILE 782      // ceil(N_NODES / 128)
#define NBLK_MLP 512   // 2 tiles/block, exactly 2 blocks/CU -> balanced grid barrier

typedef __bf16 bf16_t;
typedef __bf16 bf16x8 __attribute__((ext_vector_type(8)));
typedef __bf16 bf16x4 __attribute__((ext_vector_type(4)));
typedef __bf16 bf16x2 __attribute__((ext_vector_type(2)));
typedef float f32x4 __attribute__((ext_vector_type(4)));

// ---------------- setup: counting sort by dst ----------------

__global__ void k_count(const int* __restrict__ dst, int* __restrict__ counts) {
    int e = blockIdx.x * 256 + threadIdx.x;
    if (e < N_EDGES) atomicAdd(&counts[dst[e]], 1);
}

__global__ void k_scan1(const int* __restrict__ counts, int* __restrict__ row_ptr,
                        int* __restrict__ blk) {
    __shared__ int s[1024];
    int i = blockIdx.x * 1024 + threadIdx.x;
    int v = (i < N_NODES) ? counts[i] : 0;
    s[threadIdx.x] = v;
    __syncthreads();
    for (int off = 1; off < 1024; off <<= 1) {
        int u = (threadIdx.x >= off) ? s[threadIdx.x - off] : 0;
        __syncthreads();
        s[threadIdx.x] += u;
        __syncthreads();
    }
    if (i < N_NODES) row_ptr[i] = s[threadIdx.x] - v;   // block-local exclusive
    if (threadIdx.x == 1023) blk[blockIdx.x] = s[1023]; // block total
}

__global__ void k_scan2(int* __restrict__ blk) { // exclusive scan of 98 block totals
    __shared__ int s[128];
    int t = threadIdx.x;
    int v = (t < 98) ? blk[t] : 0;
    s[t] = v;
    __syncthreads();
    for (int off = 1; off < 128; off <<= 1) {
        int u = (t >= off) ? s[t - off] : 0;
        __syncthreads();
        s[t] += u;
        __syncthreads();
    }
    if (t < 98) blk[t] = s[t] - v;
}

__global__ void k_scan3(const int* __restrict__ blk, int* __restrict__ row_ptr) {
    int i = blockIdx.x * 1024 + threadIdx.x;
    if (i < N_NODES) row_ptr[i] += blk[blockIdx.x];
    if (i == 0) row_ptr[N_NODES] = N_EDGES;
}

// merged scatter+permute, 16 lanes per edge in ORIGINAL edge order:
// ea read is coalesced streaming (was: random 256B gather over 205MB = the
// latency bottleneck), pe gathers are L3-resident (25.6MB), feat/edat writes
// are scattered 256B/16B (fire-and-forget, no stall).
// feat[pos] = [z_re(32) | z_im(32) | ea(64)] bf16; edat[pos]={src,dst,graph,e}.
__global__ void k_build(const int* __restrict__ ei, const int* __restrict__ batch,
                        const int* __restrict__ row_ptr, int* __restrict__ cursor,
                        int4* __restrict__ edat, const float* __restrict__ pe,
                        const float* __restrict__ ea, bf16_t* __restrict__ feat) {
    int t = blockIdx.x * 256 + threadIdx.x;
    int g = t >> 4, k = t & 15;          // one 16-lane group per edge; grid exact
    int s = ei[g], d = ei[N_EDGES + g];  // same addr across group -> broadcast load
    int pos = 0;
    if (k == 0) {
        pos = row_ptr[d] + atomicAdd(&cursor[d], 1);
        edat[pos] = make_int4(s, d, batch[s], g);
    }
    pos = __shfl(pos, (threadIdx.x & 63) & ~15);
    f32x4 av = *(const f32x4*)(ea + (size_t)g * 64 + k * 4);   // coalesced
    f32x4 sv = *(const f32x4*)(pe + (size_t)s * 64 + k * 4);   // L3-hit gather
    f32x4 dv = *(const f32x4*)(pe + (size_t)d * 64 + k * 4);
    bf16x4 ao;
#pragma unroll
    for (int i = 0; i < 4; i++) ao[i] = (bf16_t)av[i];
    bf16x2 re, im;
    re[0] = (bf16_t)(sv[0] * dv[0] + sv[1] * dv[1]);
    re[1] = (bf16_t)(sv[2] * dv[2] + sv[3] * dv[3]);
    im[0] = (bf16_t)(sv[1] * dv[0] - sv[0] * dv[1]);
    im[1] = (bf16_t)(sv[3] * dv[2] - sv[2] * dv[3]);
    bf16_t* f = feat + (size_t)pos * 128;
    *(bf16x2*)(f + 2 * k) = re;
    *(bf16x2*)(f + 32 + 2 * k) = im;
    *(bf16x4*)(f + 64 + 4 * k) = ao;
}

// ---------------- weight prep ----------------

__global__ void k_phi(const float* __restrict__ Lam, const float* __restrict__ w1,
                      const float* __restrict__ b1, const float* __restrict__ w2,
                      const float* __restrict__ b2, bf16_t* __restrict__ w_all) {
    int idx = blockIdx.x * 256 + threadIdx.x;
    if (idx >= NL * NB * QM) return;
    int l = idx / (NB * QM);
    int rem = idx % (NB * QM);
    float lam = Lam[rem];
    float acc = b2[l];
    for (int i = 0; i < 16; i++) {
        float h = lam * w1[l * 16 + i] + b1[l * 16 + i];
        acc += fmaxf(h, 0.f) * w2[l * 16 + i];
    }
    w_all[idx] = (bf16_t)acc;
}

__global__ void k_prep(const float* __restrict__ enc_w, const float* __restrict__ enc_b,
                       const float* __restrict__ lin_w, const float* __restrict__ lin_b,
                       const float* __restrict__ mlp_w1, const float* __restrict__ mlp_w2,
                       bf16_t* __restrict__ wcat_frag, bf16_t* __restrict__ w1frag,
                       bf16_t* __restrict__ w2frag, float* __restrict__ cvec) {
    __shared__ float lds[128][64];
    int l = blockIdx.x, tid = threadIdx.x;
    const float* ew = enc_w + l * 64 * 64;
    const float* lw = lin_w + l * 64 * 64;
    for (int idx = tid; idx < 64 * 64; idx += 256) {
        int r = idx >> 6, c = idx & 63;
        float acc = 0.f;
        for (int k = 0; k < 64; k++) acc += ew[r * 64 + k] * lw[k * 64 + c];
        lds[r][c] = acc;
        lds[64 + r][c] = lw[r * 64 + c];
    }
    if (tid < 64) {
        float acc = lin_b[l * 64 + tid];
        for (int k = 0; k < 64; k++) acc += enc_b[l * 64 + k] * lw[k * 64 + tid];
        cvec[l * 64 + tid] = acc;
    }
    __syncthreads();
    for (int idx = tid; idx < 16 * 512; idx += 256) {
        int sn = idx >> 9, lane = (idx >> 3) & 63, j = idx & 7;
        int s = sn >> 2, nt = sn & 3;
        int row = 32 * s + (lane >> 4) * 8 + j;
        int col = 16 * nt + (lane & 15);
        wcat_frag[l * 8192 + idx] = (bf16_t)lds[row][col];
    }
    for (int idx = tid; idx < 8 * 512; idx += 256) {
        int sn = idx >> 9, lane = (idx >> 3) & 63, j = idx & 7;
        int s = sn >> 2, nt = sn & 3;
        int row = 32 * s + (lane >> 4) * 8 + j; // k index
        int col = 16 * nt + (lane & 15);
        w1frag[l * 4096 + idx] = (bf16_t)mlp_w1[(l * 64 + row) * 64 + col];
        w2frag[l * 4096 + idx] = (bf16_t)mlp_w2[(l * 64 + row) * 64 + col];
    }
}

// ---------------- per-layer kernels ----------------

// layer 0 init: x_bf = bf16(x), h = x; also pe passthrough to out (replaces memcpy)
__global__ void k_hinit0(const float* __restrict__ x, const float* __restrict__ pe,
                         bf16_t* __restrict__ x_bf, float* __restrict__ h,
                         float* __restrict__ out_pe) {
    size_t i = ((size_t)blockIdx.x * 256 + threadIdx.x) * 8;
    f32x4 a = *(const f32x4*)(x + i), b = *(const f32x4*)(x + i + 4);
    *(f32x4*)(h + i) = a;
    *(f32x4*)(h + i + 4) = b;
    bf16x8 o;
#pragma unroll
    for (int k = 0; k < 4; k++) { o[k] = (bf16_t)a[k]; o[k + 4] = (bf16_t)b[k]; }
    *(bf16x8*)(x_bf + i) = o;
    f32x4 p0 = *(const f32x4*)(pe + i), p1 = *(const f32x4*)(pe + i + 4);
    *(f32x4*)(out_pe + i) = p0;
    *(f32x4*)(out_pe + i + 4) = p1;
}

// 128 dst-sorted edges per block: msg = relu(x[src] + feat @ Wcat + cvec),
// then in-block segment sum into h (h pre-initialized to x).
__global__ void k_edge(const bf16_t* __restrict__ feat, const int4* __restrict__ edat,
                       const int* __restrict__ row_ptr, const bf16_t* __restrict__ w_l,
                       const bf16_t* __restrict__ wcat_l, const float* __restrict__ cvec_l,
                       const bf16_t* __restrict__ x_bf, float* __restrict__ h) {
    __shared__ float msg[128][68];
    int tid = threadIdx.x;
    int wave = tid >> 6, lane = tid & 63;
    int quad = lane >> 4, l16 = lane & 15;
    int e0 = blockIdx.x * 128;

    bf16x8 bfrag[4][4];
    const bf16x8* wf = (const bf16x8*)wcat_l;
#pragma unroll
    for (int s = 0; s < 4; s++)
#pragma unroll
        for (int nt = 0; nt < 4; nt++) bfrag[s][nt] = wf[(s * 4 + nt) * 64 + lane];

    f32x4 acc[2][4];
#pragma unroll
    for (int rt = 0; rt < 2; rt++)
#pragma unroll
        for (int nt = 0; nt < 4; nt++) acc[rt][nt] = (f32x4)(0.f);

    int em[2];
    bf16x8 wch[2];
#pragma unroll
    for (int rt = 0; rt < 2; rt++) {
        em[rt] = e0 + wave * 32 + rt * 16 + l16;
        int eg = edat[em[rt]].z;
        wch[rt] = *(const bf16x8*)(w_l + (size_t)eg * QM + quad * 8);
    }
#pragma unroll
    for (int s = 0; s < 4; s++) {
        bf16x8 afr[2];
#pragma unroll
        for (int rt = 0; rt < 2; rt++) {
            bf16x8 v = *(const bf16x8*)(feat + (size_t)em[rt] * 128 + s * 32 + quad * 8);
            if (s < 2) {
                bf16x8 a;
#pragma unroll
                for (int i = 0; i < 8; i++) a[i] = (bf16_t)((float)v[i] * (float)wch[rt][i]);
                afr[rt] = a;
            } else {
                afr[rt] = v;
            }
        }
#pragma unroll
        for (int rt = 0; rt < 2; rt++)
#pragma unroll
            for (int nt = 0; nt < 4; nt++)
                acc[rt][nt] = __builtin_amdgcn_mfma_f32_16x16x32_bf16(afr[rt], bfrag[s][nt],
                                                                     acc[rt][nt], 0, 0, 0);
    }
    // C layout: row = quad*4 + r, col = lane&15 (per 16x16 tile)
#pragma unroll
    for (int nt = 0; nt < 4; nt++) {
        float cv = cvec_l[nt * 16 + l16];
#pragma unroll
        for (int rt = 0; rt < 2; rt++)
#pragma unroll
            for (int r = 0; r < 4; r++)
                msg[wave * 32 + rt * 16 + quad * 4 + r][nt * 16 + l16] = acc[rt][nt][r] + cv;
    }
    __syncthreads();
    // add x[src] (bf16 row = 128B per 8-lane group), relu
#pragma unroll
    for (int it = 0; it < 4; it++) {
        int j = it * 32 + (tid >> 3);
        int l8 = tid & 7;
        int srcn = edat[e0 + j].x;
        bf16x8 xv = *(const bf16x8*)(x_bf + (size_t)srcn * 64 + l8 * 8);
        float* mrow = &msg[j][l8 * 8];
        f32x4 m0 = *(const f32x4*)mrow, m1 = *(const f32x4*)(mrow + 4);
#pragma unroll
        for (int k = 0; k < 4; k++) {
            m0[k] = fmaxf(m0[k] + (float)xv[k], 0.f);
            m1[k] = fmaxf(m1[k] + (float)xv[k + 4], 0.f);
        }
        *(f32x4*)mrow = m0;
        *(f32x4*)(mrow + 4) = m1;
    }
    __syncthreads();
    // segment reduce over this block's edge window
    int nfirst = edat[e0].y, nlast = edat[e0 + 127].y;
    int c = tid & 63;
    for (int n = nfirst + (tid >> 6); n <= nlast; n += 4) {
        int rs = row_ptr[n], re = row_ptr[n + 1];
        int a = rs > e0 ? rs : e0;
        int b = re < e0 + 128 ? re : e0 + 128;
        if (a >= b) continue;
        float sum = 0.f;
        for (int jj = a; jj < b; jj++) sum += msg[jj - e0][c];
        float* addr = h + (size_t)n * 64 + c;
        if (rs >= e0 && re <= e0 + 128) *addr += sum;  // sole owner
        else atomicAdd(addr, sum);                     // boundary node
    }
}

// ---- fused MLP: t = h@w1+b1 -> BN1 -> relu -> @w2+b2 -> BN2 [-> relu] ----
// One kernel, two grid barriers. 512 blocks = exactly 2/CU (balanced; R7
// showed non-multiple-of-256 grids straggle at the barrier). Contended
// atomics sharded x8 (R8: -64us): stats are 8 shadow copies summed at use;
// barrier is 8 counters on separate 128B lines, spinners poll the sum.
// RELEASE arrive + RELAXED spin only (acquire-per-poll invalidates XCD L2
// every iteration -> R4's 60us/barrier). t in swizzled LDS; h2 in VGPRs
// across the BN2 barrier; phase 3 goes through LDS for coalesced stores.

__device__ __forceinline__ int swz_idx(int row, int col) {
    // bf16 element index with byte-XOR swizzle; keeps 16B alignment for b128 ops
    return ((row * 128 + col * 2) ^ ((row & 7) << 4)) >> 1;
}

__device__ __forceinline__ void gbar(int* bars, int target) {
    __syncthreads();
    if (threadIdx.x == 0) {
        __hip_atomic_fetch_add(bars + (blockIdx.x & 7) * 32, 1,
                               __ATOMIC_RELEASE, __HIP_MEMORY_SCOPE_AGENT);
        int s;
        do {
            s = 0;
#pragma unroll
            for (int j = 0; j < 8; j++)
                s += __hip_atomic_load(bars + j * 32, __ATOMIC_RELAXED,
                                       __HIP_MEMORY_SCOPE_AGENT);
            if (s < target) __builtin_amdgcn_s_sleep(16);
        } while (s < target);
    }
    __syncthreads();
}

template <int LAST>
__global__ __launch_bounds__(256, 2) void k_mlp(
    const float* __restrict__ h, const bf16_t* __restrict__ w1frag_l,
    const bf16_t* __restrict__ w2frag_l, const float* __restrict__ b1_l,
    const float* __restrict__ g1, const float* __restrict__ bb1,
    const float* __restrict__ b2_l, const float* __restrict__ g2,
    const float* __restrict__ bb2, float* __restrict__ stats1,
    float* __restrict__ stats2, int* __restrict__ bars, float* __restrict__ hout,
    bf16_t* __restrict__ x_bf, float* __restrict__ out) {
    // sbuf: phases 1-2 = two 128x64 bf16 t-tiles (swizzled);
    // phase 3 = one [128][68] f32 tile (h2 transpose for coalesced stores).
    __shared__ __align__(16) char sbuf[34816];
    __shared__ float sred[128];
    __shared__ float cf[128];
    bf16_t* tls0 = (bf16_t*)sbuf;
    bf16_t* tls1 = (bf16_t*)(sbuf + 16384);
    float (*fls)[68] = (float(*)[68])sbuf;
    int tid = threadIdx.x, wave = tid >> 6, lane = tid & 63, quad = lane >> 4, l16 = lane & 15;
    int shard = (blockIdx.x & 7) * 128;

    bf16x8 bfrag[2][4];
    const bf16x8* wf1 = (const bf16x8*)w1frag_l;
#pragma unroll
    for (int s = 0; s < 2; s++)
#pragma unroll
        for (int nt = 0; nt < 4; nt++) bfrag[s][nt] = wf1[(s * 4 + nt) * 64 + lane];

    if (tid < 128) sred[tid] = 0.f;
    __syncthreads();

    // ---- phase 1: t-tiles + BN1 stats ----
#pragma unroll
    for (int ti = 0; ti < 2; ti++) {
        int tile = blockIdx.x + ti * NBLK_MLP;
        if (tile >= NTILE) continue;
        bf16_t* tl = ti ? tls1 : tls0;
        int r0 = tile * 128;
        f32x4 acc[2][4];
#pragma unroll
        for (int rt = 0; rt < 2; rt++)
#pragma unroll
            for (int nt = 0; nt < 4; nt++) acc[rt][nt] = (f32x4)(0.f);
#pragma unroll
        for (int rt = 0; rt < 2; rt++) {
            int n = r0 + wave * 32 + rt * 16 + l16;
            bool valid = n < N_NODES;
#pragma unroll
            for (int s = 0; s < 2; s++) {
                bf16x8 a;
                if (valid) {
                    const float* hp = h + (size_t)n * 64 + s * 32 + quad * 8;
                    f32x4 v0 = *(const f32x4*)hp, v1 = *(const f32x4*)(hp + 4);
#pragma unroll
                    for (int i = 0; i < 4; i++) { a[i] = (bf16_t)v0[i]; a[i + 4] = (bf16_t)v1[i]; }
                } else {
#pragma unroll
                    for (int i = 0; i < 8; i++) a[i] = (bf16_t)0.f;
                }
#pragma unroll
                for (int nt = 0; nt < 4; nt++)
                    acc[rt][nt] = __builtin_amdgcn_mfma_f32_16x16x32_bf16(a, bfrag[s][nt],
                                                                         acc[rt][nt], 0, 0, 0);
            }
        }
#pragma unroll
        for (int nt = 0; nt < 4; nt++) {
            int col = nt * 16 + l16;
            float bias = b1_l[col];
            float s1 = 0.f, s2 = 0.f;
#pragma unroll
            for (int rt = 0; rt < 2; rt++)
#pragma unroll
                for (int r = 0; r < 4; r++) {
                    int rloc = wave * 32 + rt * 16 + quad * 4 + r;
                    int n = r0 + rloc;
                    if (n < N_NODES) {
                        float v = acc[rt][nt][r] + bias;
                        tl[swz_idx(rloc, col)] = (bf16_t)v;
                        s1 += v; s2 += v * v;
                    } else {
                        tl[swz_idx(rloc, col)] = (bf16_t)0.f;
                    }
                }
            s1 += __shfl_xor(s1, 16); s1 += __shfl_xor(s1, 32);
            s2 += __shfl_xor(s2, 16); s2 += __shfl_xor(s2, 32);
            if (quad == 0) { atomicAdd(&sred[col], s1); atomicAdd(&sred[64 + col], s2); }
        }
    }
    __syncthreads();
    if (tid < 128) atomicAdd(&stats1[shard + tid], sred[tid]);
    gbar(bars, NBLK_MLP);

    // ---- phase 2: BN1 coefs (sum 8 shards), second GEMM (h2 in registers) ----
    if (tid < 128) sred[tid] = 0.f;
    if (tid < 64) {
        float sa = 0.f, sb = 0.f;
#pragma unroll
        for (int j = 0; j < 8; j++) {
            sa += __hip_atomic_load(stats1 + j * 128 + tid, __ATOMIC_RELAXED,
                                    __HIP_MEMORY_SCOPE_AGENT);
            sb += __hip_atomic_load(stats1 + j * 128 + 64 + tid, __ATOMIC_RELAXED,
                                    __HIP_MEMORY_SCOPE_AGENT);
        }
        float mean = sa / (float)N_NODES;
        float var = sb / (float)N_NODES - mean * mean;
        float a = g1[tid] * rsqrtf(var + EPS_BN);
        cf[tid] = a;
        cf[64 + tid] = bb1[tid] - mean * a;
    }
    __syncthreads();

    bf16x8 b2frag[2][4];
    const bf16x8* wf2 = (const bf16x8*)w2frag_l;
#pragma unroll
    for (int s = 0; s < 2; s++)
#pragma unroll
        for (int nt = 0; nt < 4; nt++) b2frag[s][nt] = wf2[(s * 4 + nt) * 64 + lane];

    f32x4 acc2[2][2][4];
#pragma unroll
    for (int ti = 0; ti < 2; ti++)
#pragma unroll
        for (int rt = 0; rt < 2; rt++)
#pragma unroll
            for (int nt = 0; nt < 4; nt++) acc2[ti][rt][nt] = (f32x4)(0.f);

#pragma unroll
    for (int ti = 0; ti < 2; ti++) {
        int tile = blockIdx.x + ti * NBLK_MLP;
        if (tile >= NTILE) continue;
        bf16_t* tl = ti ? tls1 : tls0;
#pragma unroll
        for (int rt = 0; rt < 2; rt++) {
            int rloc = wave * 32 + rt * 16 + l16;
#pragma unroll
            for (int s = 0; s < 2; s++) {
                int k0 = s * 32 + quad * 8;
                bf16x8 tv = *(const bf16x8*)&tl[swz_idx(rloc, k0)];
                bf16x8 a;
#pragma unroll
                for (int i = 0; i < 8; i++) {
                    float y = (float)tv[i] * cf[k0 + i] + cf[64 + k0 + i];
                    a[i] = (bf16_t)fmaxf(y, 0.f);
                }
#pragma unroll
                for (int nt = 0; nt < 4; nt++)
                    acc2[ti][rt][nt] = __builtin_amdgcn_mfma_f32_16x16x32_bf16(
                        a, b2frag[s][nt], acc2[ti][rt][nt], 0, 0, 0);
            }
        }
    }

    // BN2 stats from register-resident h2
#pragma unroll
    for (int nt = 0; nt < 4; nt++) {
        int col = nt * 16 + l16;
        float bias = b2_l[col];
        float s1 = 0.f, s2 = 0.f;
#pragma unroll
        for (int ti = 0; ti < 2; ti++) {
            int tile = blockIdx.x + ti * NBLK_MLP;
            if (tile >= NTILE) continue;
            int r0 = tile * 128;
#pragma unroll
            for (int rt = 0; rt < 2; rt++)
#pragma unroll
                for (int r = 0; r < 4; r++) {
                    int n = r0 + wave * 32 + rt * 16 + quad * 4 + r;
                    if (n < N_NODES) {
                        float v = acc2[ti][rt][nt][r] + bias;
                        s1 += v; s2 += v * v;
                    }
                }
        }
        s1 += __shfl_xor(s1, 16); s1 += __shfl_xor(s1, 32);
        s2 += __shfl_xor(s2, 16); s2 += __shfl_xor(s2, 32);
        if (quad == 0) { atomicAdd(&sred[col], s1); atomicAdd(&sred[64 + col], s2); }
    }
    __syncthreads();
    if (tid < 128) atomicAdd(&stats2[shard + tid], sred[tid]);
    gbar(bars, 2 * NBLK_MLP);

    // ---- phase 3: BN2 coefs (sum 8 shards), h2 -> LDS -> coalesced stores ----
    if (tid < 64) {
        float sa = 0.f, sb = 0.f;
#pragma unroll
        for (int j = 0; j < 8; j++) {
            sa += __hip_atomic_load(stats2 + j * 128 + tid, __ATOMIC_RELAXED,
                                    __HIP_MEMORY_SCOPE_AGENT);
            sb += __hip_atomic_load(stats2 + j * 128 + 64 + tid, __ATOMIC_RELAXED,
                                    __HIP_MEMORY_SCOPE_AGENT);
        }
        float mean = sa / (float)N_NODES;
        float var = sb / (float)N_NODES - mean * mean;
        float a = g2[tid] * rsqrtf(var + EPS_BN);
        cf[tid] = a;
        cf[64 + tid] = bb2[tid] - mean * a;
    }
#pragma unroll
    for (int ti = 0; ti < 2; ti++) {
        int tile = blockIdx.x + ti * NBLK_MLP;
        if (tile >= NTILE) continue;   // block-uniform: all threads agree
        __syncthreads();               // fls free (tls dead / prev tile done); cf visible
        int r0 = tile * 128;
#pragma unroll
        for (int nt = 0; nt < 4; nt++) {
            int col = nt * 16 + l16;
            float bias = b2_l[col];
#pragma unroll
            for (int rt = 0; rt < 2; rt++)
#pragma unroll
                for (int r = 0; r < 4; r++)
                    fls[wave * 32 + rt * 16 + quad * 4 + r][col] = acc2[ti][rt][nt][r] + bias;
        }
        __syncthreads();
#pragma unroll
        for (int pass = 0; pass < 4; pass++) {
            int rloc = pass * 32 + (tid >> 3);
            int n = r0 + rloc;
            if (n >= N_NODES) continue;
            int c0 = (tid & 7) * 8;
            f32x4 v0 = *(const f32x4*)&fls[rloc][c0];
            f32x4 v1 = *(const f32x4*)&fls[rloc][c0 + 4];
            f32x4 y0, y1;
#pragma unroll
            for (int k = 0; k < 4; k++) {
                y0[k] = v0[k] * cf[c0 + k] + cf[64 + c0 + k];
                y1[k] = v1[k] * cf[c0 + 4 + k] + cf[64 + c0 + 4 + k];
            }
            if (LAST) {
                *(f32x4*)(out + (size_t)n * 64 + c0) = y0;
                *(f32x4*)(out + (size_t)n * 64 + c0 + 4) = y1;
            } else {
                bf16x8 o;
#pragma unroll
                for (int k = 0; k < 4; k++) {
                    y0[k] = fmaxf(y0[k], 0.f);
                    y1[k] = fmaxf(y1[k], 0.f);
                    o[k] = (bf16_t)y0[k]; o[k + 4] = (bf16_t)y1[k];
                }
                *(f32x4*)(hout + (size_t)n * 64 + c0) = y0;
                *(f32x4*)(hout + (size_t)n * 64 + c0 + 4) = y1;
                *(bf16x8*)(x_bf + (size_t)n * 64 + c0) = o;
            }
        }
    }
}

// ---------------- host ----------------

extern "C" void kernel_launch(void* const* d_in, const int* in_sizes, int n_in,
                              void* d_out, int out_size, void* d_ws, size_t ws_size,
                              hipStream_t stream) {
    const float* x_in   = (const float*)d_in[0];
    const float* pe     = (const float*)d_in[1];
    const float* Lam    = (const float*)d_in[2];
    const float* eattr  = (const float*)d_in[3];
    const float* phi_w1 = (const float*)d_in[4];
    const float* phi_b1 = (const float*)d_in[5];
    const float* phi_w2 = (const float*)d_in[6];
    const float* phi_b2 = (const float*)d_in[7];
    const float* enc_w  = (const float*)d_in[8];
    const float* enc_b  = (const float*)d_in[9];
    const float* lin_w  = (const float*)d_in[10];
    const float* lin_b  = (const float*)d_in[11];
    const float* mlp_w1 = (const float*)d_in[12];
    const float* mlp_b1 = (const float*)d_in[13];
    const float* bn1_g  = (const float*)d_in[14];
    const float* bn1_b  = (const float*)d_in[15];
    const float* mlp_w2 = (const float*)d_in[16];
    const float* mlp_b2 = (const float*)d_in[17];
    const float* bn2_g  = (const float*)d_in[18];
    const float* bn2_b  = (const float*)d_in[19];
    const int* edge_index = (const int*)d_in[20];
    const int* batch      = (const int*)d_in[21];
    float* out = (float*)d_out;

    char* ws = (char*)d_ws;
    size_t off = 0;
    auto alloc = [&](size_t bytes) -> void* {
        void* p = ws + off;
        off += (bytes + 255) & ~(size_t)255;
        return p;
    };
    bf16_t* feat      = (bf16_t*)alloc((size_t)N_EDGES * 128 * 2);
    int4* edat        = (int4*)alloc((size_t)N_EDGES * 16);
    int* row_ptr      = (int*)alloc((size_t)(N_NODES + 1) * 4);
    int* blk          = (int*)alloc(128 * 4);
    // zero-init region (one memset): counts | cursor | stats(8-shard) | bar(8-shard)
    int* counts       = (int*)alloc((size_t)N_NODES * 4);
    int* cursor       = (int*)alloc((size_t)N_NODES * 4);
    float* stats      = (float*)alloc((size_t)NL * 2048 * 4); // per layer: s1[8][128], s2[8][128]
    int* bar          = (int*)alloc((size_t)NL * 256 * 4);    // per layer: 8 counters, 128B apart
    size_t zbytes     = (char*)(bar + NL * 256) - (char*)counts;
    float* h          = (float*)alloc((size_t)N_NODES * 64 * 4);
    bf16_t* x_bf      = (bf16_t*)alloc((size_t)N_NODES * 64 * 2);
    bf16_t* w_all     = (bf16_t*)alloc((size_t)NL * NB * QM * 2);
    bf16_t* wcat_frag = (bf16_t*)alloc((size_t)NL * 8192 * 2);
    bf16_t* w1frag    = (bf16_t*)alloc((size_t)NL * 4096 * 2);
    bf16_t* w2frag    = (bf16_t*)alloc((size_t)NL * 4096 * 2);
    float* cvec       = (float*)alloc((size_t)NL * 64 * 4);

    // ---- one-time setup ----
    hipMemsetAsync(counts, 0, zbytes, stream);
    k_count<<<3125, 256, 0, stream>>>(edge_index + N_EDGES, counts);
    k_scan1<<<98, 1024, 0, stream>>>(counts, row_ptr, blk);
    k_scan2<<<1, 128, 0, stream>>>(blk);
    k_scan3<<<98, 1024, 0, stream>>>(blk, row_ptr);
    k_build<<<50000, 256, 0, stream>>>(edge_index, batch, row_ptr, cursor, edat,
                                       pe, eattr, feat);
    k_phi<<<50, 256, 0, stream>>>(Lam, phi_w1, phi_b1, phi_w2, phi_b2, w_all);
    k_prep<<<NL, 256, 0, stream>>>(enc_w, enc_b, lin_w, lin_b, mlp_w1, mlp_w2,
                                   wcat_frag, w1frag, w2frag, cvec);

    // ---- layers ----
    k_hinit0<<<3125, 256, 0, stream>>>(x_in, pe, x_bf, h, out + (size_t)N_NODES * 64);
    for (int l = 0; l < NL; l++) {
        float* s1 = stats + (size_t)l * 2048;
        float* s2 = stats + (size_t)l * 2048 + 1024;
        int* bl = bar + (size_t)l * 256;
        k_edge<<<6250, 256, 0, stream>>>(feat, edat, row_ptr,
                                         w_all + (size_t)l * NB * QM,
                                         wcat_frag + (size_t)l * 8192,
                                         cvec + (size_t)l * 64, x_bf, h);
        if (l < NL - 1)
            k_mlp<0><<<NBLK_MLP, 256, 0, stream>>>(
                h, w1frag + (size_t)l * 4096, w2frag + (size_t)l * 4096,
                mlp_b1 + l * 64, bn1_g + l * 64, bn1_b + l * 64,
                mlp_b2 + l * 64, bn2_g + l * 64, bn2_b + l * 64,
                s1, s2, bl, h, x_bf, (float*)nullptr);
        else
            k_mlp<1><<<NBLK_MLP, 256, 0, stream>>>(
                h, w1frag + (size_t)l * 4096, w2frag + (size_t)l * 4096,
                mlp_b1 + l * 64, bn1_g + l * 64, bn1_b + l * 64,
                mlp_b2 + l * 64, bn2_g + l * 64, bn2_b + l * 64,
                s1, s2, bl, h, x_bf, out);
    }
}

// Round 13
// 1085.137 us; speedup vs baseline: 1.1845x; 1.0045x over previous
//
#include <hip/hip_runtime.h>

#define N_NODES 100000
#define N_EDGES 800000
#define NB 100
#define NL 4
#define QM 32
#define EPS_BN 1e-5f
#define NTILE 782      // ceil(N_NODES / 128)
#define NBLK_MLP 512   // 2 tiles/block, exactly 2 blocks/CU -> balanced grid barrier

typedef __bf16 bf16_t;
typedef __bf16 bf16x8 __attribute__((ext_vector_type(8)));
typedef __bf16 bf16x4 __attribute__((ext_vector_type(4)));
typedef __bf16 bf16x2 __attribute__((ext_vector_type(2)));
typedef float f32x4 __attribute__((ext_vector_type(4)));
typedef unsigned int u32;
typedef unsigned long long u64;

// ---------------- setup: counting sort by dst ----------------

__global__ void k_count(const int* __restrict__ dst, int* __restrict__ counts) {
    int e = blockIdx.x * 256 + threadIdx.x;
    if (e < N_EDGES) atomicAdd(&counts[dst[e]], 1);
}

__global__ void k_scan1(const int* __restrict__ counts, int* __restrict__ row_ptr,
                        int* __restrict__ blk) {
    __shared__ int s[1024];
    int i = blockIdx.x * 1024 + threadIdx.x;
    int v = (i < N_NODES) ? counts[i] : 0;
    s[threadIdx.x] = v;
    __syncthreads();
    for (int off = 1; off < 1024; off <<= 1) {
        int u = (threadIdx.x >= off) ? s[threadIdx.x - off] : 0;
        __syncthreads();
        s[threadIdx.x] += u;
        __syncthreads();
    }
    if (i < N_NODES) row_ptr[i] = s[threadIdx.x] - v;   // block-local exclusive
    if (threadIdx.x == 1023) blk[blockIdx.x] = s[1023]; // block total
}

__global__ void k_scan2(int* __restrict__ blk) { // exclusive scan of 98 block totals
    __shared__ int s[128];
    int t = threadIdx.x;
    int v = (t < 98) ? blk[t] : 0;
    s[t] = v;
    __syncthreads();
    for (int off = 1; off < 128; off <<= 1) {
        int u = (t >= off) ? s[t - off] : 0;
        __syncthreads();
        s[t] += u;
        __syncthreads();
    }
    if (t < 98) blk[t] = s[t] - v;
}

__global__ void k_scan3(const int* __restrict__ blk, int* __restrict__ row_ptr) {
    int i = blockIdx.x * 1024 + threadIdx.x;
    if (i < N_NODES) row_ptr[i] += blk[blockIdx.x];
    if (i == 0) row_ptr[N_NODES] = N_EDGES;
}

// merged scatter+permute, 16 lanes per edge in ORIGINAL edge order:
// ea read is coalesced streaming; pe gathers are L3-resident. R10 showed the
// scattered feat stores were PARTIAL-SECTOR (re/im as 2x64B per 128B line ->
// read-for-ownership, +130MB traffic). Fix: cross-lane repack via two 64-bit
// shuffles so each group writes its 256B row as two full 128B segments
// (16 lanes x 8B contiguous each). edat 16B scatter remains (unavoidable).
__global__ void k_build(const int* __restrict__ ei, const int* __restrict__ batch,
                        const int* __restrict__ row_ptr, int* __restrict__ cursor,
                        int4* __restrict__ edat, const float* __restrict__ pe,
                        const float* __restrict__ ea, bf16_t* __restrict__ feat) {
    int t = blockIdx.x * 256 + threadIdx.x;
    int g = t >> 4, k = t & 15;          // one 16-lane group per edge; grid exact
    int lane = threadIdx.x & 63;
    int base = lane & ~15;               // first lane of this group within the wave
    int s = ei[g], d = ei[N_EDGES + g];  // same addr across group -> broadcast load
    int pos = 0;
    if (k == 0) {
        pos = row_ptr[d] + atomicAdd(&cursor[d], 1);
        edat[pos] = make_int4(s, d, batch[s], g);
    }
    pos = __shfl(pos, base);
    f32x4 av = *(const f32x4*)(ea + (size_t)g * 64 + k * 4);   // coalesced
    f32x4 sv = *(const f32x4*)(pe + (size_t)s * 64 + k * 4);   // L3-hit gather
    f32x4 dv = *(const f32x4*)(pe + (size_t)d * 64 + k * 4);
    bf16x4 ao;
#pragma unroll
    for (int i = 0; i < 4; i++) ao[i] = (bf16_t)av[i];
    bf16x2 re, im;
    re[0] = (bf16_t)(sv[0] * dv[0] + sv[1] * dv[1]);
    re[1] = (bf16_t)(sv[2] * dv[2] + sv[3] * dv[3]);
    im[0] = (bf16_t)(sv[1] * dv[0] - sv[0] * dv[1]);
    im[1] = (bf16_t)(sv[3] * dv[2] - sv[2] * dv[3]);
    // repack z across the group: lane k collects z-row elements 4k..4k+3
    // (re for k<8, im for k>=8) from lanes 2*(k&7) and 2*(k&7)+1.
    u64 z = ((u64)(*(u32*)&im) << 32) | (u64)(*(u32*)&re);
    u64 za = __shfl(z, base + 2 * (k & 7));
    u64 zb = __shfl(z, base + 2 * (k & 7) + 1);
    u32 lo = (k < 8) ? (u32)za : (u32)(za >> 32);
    u32 hi = (k < 8) ? (u32)zb : (u32)(zb >> 32);
    bf16_t* f = feat + (size_t)pos * 128;
    uint2 zw = make_uint2(lo, hi);
    *(uint2*)(f + 4 * k) = zw;            // bytes 0..127: full segment per group
    *(bf16x4*)(f + 64 + 4 * k) = ao;      // bytes 128..255: full segment per group
}

// ---------------- weight prep ----------------

__global__ void k_phi(const float* __restrict__ Lam, const float* __restrict__ w1,
                      const float* __restrict__ b1, const float* __restrict__ w2,
                      const float* __restrict__ b2, bf16_t* __restrict__ w_all) {
    int idx = blockIdx.x * 256 + threadIdx.x;
    if (idx >= NL * NB * QM) return;
    int l = idx / (NB * QM);
    int rem = idx % (NB * QM);
    float lam = Lam[rem];
    float acc = b2[l];
    for (int i = 0; i < 16; i++) {
        float h = lam * w1[l * 16 + i] + b1[l * 16 + i];
        acc += fmaxf(h, 0.f) * w2[l * 16 + i];
    }
    w_all[idx] = (bf16_t)acc;
}

__global__ void k_prep(const float* __restrict__ enc_w, const float* __restrict__ enc_b,
                       const float* __restrict__ lin_w, const float* __restrict__ lin_b,
                       const float* __restrict__ mlp_w1, const float* __restrict__ mlp_w2,
                       bf16_t* __restrict__ wcat_frag, bf16_t* __restrict__ w1frag,
                       bf16_t* __restrict__ w2frag, float* __restrict__ cvec) {
    __shared__ float lds[128][64];
    int l = blockIdx.x, tid = threadIdx.x;
    const float* ew = enc_w + l * 64 * 64;
    const float* lw = lin_w + l * 64 * 64;
    for (int idx = tid; idx < 64 * 64; idx += 256) {
        int r = idx >> 6, c = idx & 63;
        float acc = 0.f;
        for (int k = 0; k < 64; k++) acc += ew[r * 64 + k] * lw[k * 64 + c];
        lds[r][c] = acc;
        lds[64 + r][c] = lw[r * 64 + c];
    }
    if (tid < 64) {
        float acc = lin_b[l * 64 + tid];
        for (int k = 0; k < 64; k++) acc += enc_b[l * 64 + k] * lw[k * 64 + tid];
        cvec[l * 64 + tid] = acc;
    }
    __syncthreads();
    for (int idx = tid; idx < 16 * 512; idx += 256) {
        int sn = idx >> 9, lane = (idx >> 3) & 63, j = idx & 7;
        int s = sn >> 2, nt = sn & 3;
        int row = 32 * s + (lane >> 4) * 8 + j;
        int col = 16 * nt + (lane & 15);
        wcat_frag[l * 8192 + idx] = (bf16_t)lds[row][col];
    }
    for (int idx = tid; idx < 8 * 512; idx += 256) {
        int sn = idx >> 9, lane = (idx >> 3) & 63, j = idx & 7;
        int s = sn >> 2, nt = sn & 3;
        int row = 32 * s + (lane >> 4) * 8 + j; // k index
        int col = 16 * nt + (lane & 15);
        w1frag[l * 4096 + idx] = (bf16_t)mlp_w1[(l * 64 + row) * 64 + col];
        w2frag[l * 4096 + idx] = (bf16_t)mlp_w2[(l * 64 + row) * 64 + col];
    }
}

// ---------------- per-layer kernels ----------------

// layer 0 init: x_bf = bf16(x), h = x; also pe passthrough to out (replaces memcpy)
__global__ void k_hinit0(const float* __restrict__ x, const float* __restrict__ pe,
                         bf16_t* __restrict__ x_bf, float* __restrict__ h,
                         float* __restrict__ out_pe) {
    size_t i = ((size_t)blockIdx.x * 256 + threadIdx.x) * 8;
    f32x4 a = *(const f32x4*)(x + i), b = *(const f32x4*)(x + i + 4);
    *(f32x4*)(h + i) = a;
    *(f32x4*)(h + i + 4) = b;
    bf16x8 o;
#pragma unroll
    for (int k = 0; k < 4; k++) { o[k] = (bf16_t)a[k]; o[k + 4] = (bf16_t)b[k]; }
    *(bf16x8*)(x_bf + i) = o;
    f32x4 p0 = *(const f32x4*)(pe + i), p1 = *(const f32x4*)(pe + i + 4);
    *(f32x4*)(out_pe + i) = p0;
    *(f32x4*)(out_pe + i + 4) = p1;
}

// 128 dst-sorted edges per block: msg = relu(x[src] + feat @ Wcat + cvec),
// then in-block segment sum into h (h pre-initialized to x).
__global__ void k_edge(const bf16_t* __restrict__ feat, const int4* __restrict__ edat,
                       const int* __restrict__ row_ptr, const bf16_t* __restrict__ w_l,
                       const bf16_t* __restrict__ wcat_l, const float* __restrict__ cvec_l,
                       const bf16_t* __restrict__ x_bf, float* __restrict__ h) {
    __shared__ float msg[128][68];
    int tid = threadIdx.x;
    int wave = tid >> 6, lane = tid & 63;
    int quad = lane >> 4, l16 = lane & 15;
    int e0 = blockIdx.x * 128;

    bf16x8 bfrag[4][4];
    const bf16x8* wf = (const bf16x8*)wcat_l;
#pragma unroll
    for (int s = 0; s < 4; s++)
#pragma unroll
        for (int nt = 0; nt < 4; nt++) bfrag[s][nt] = wf[(s * 4 + nt) * 64 + lane];

    f32x4 acc[2][4];
#pragma unroll
    for (int rt = 0; rt < 2; rt++)
#pragma unroll
        for (int nt = 0; nt < 4; nt++) acc[rt][nt] = (f32x4)(0.f);

    int em[2];
    bf16x8 wch[2];
#pragma unroll
    for (int rt = 0; rt < 2; rt++) {
        em[rt] = e0 + wave * 32 + rt * 16 + l16;
        int eg = edat[em[rt]].z;
        wch[rt] = *(const bf16x8*)(w_l + (size_t)eg * QM + quad * 8);
    }
#pragma unroll
    for (int s = 0; s < 4; s++) {
        bf16x8 afr[2];
#pragma unroll
        for (int rt = 0; rt < 2; rt++) {
            bf16x8 v = *(const bf16x8*)(feat + (size_t)em[rt] * 128 + s * 32 + quad * 8);
            if (s < 2) {
                bf16x8 a;
#pragma unroll
                for (int i = 0; i < 8; i++) a[i] = (bf16_t)((float)v[i] * (float)wch[rt][i]);
                afr[rt] = a;
            } else {
                afr[rt] = v;
            }
        }
#pragma unroll
        for (int rt = 0; rt < 2; rt++)
#pragma unroll
            for (int nt = 0; nt < 4; nt++)
                acc[rt][nt] = __builtin_amdgcn_mfma_f32_16x16x32_bf16(afr[rt], bfrag[s][nt],
                                                                     acc[rt][nt], 0, 0, 0);
    }
    // C layout: row = quad*4 + r, col = lane&15 (per 16x16 tile)
#pragma unroll
    for (int nt = 0; nt < 4; nt++) {
        float cv = cvec_l[nt * 16 + l16];
#pragma unroll
        for (int rt = 0; rt < 2; rt++)
#pragma unroll
            for (int r = 0; r < 4; r++)
                msg[wave * 32 + rt * 16 + quad * 4 + r][nt * 16 + l16] = acc[rt][nt][r] + cv;
    }
    __syncthreads();
    // add x[src] (bf16 row = 128B per 8-lane group), relu
#pragma unroll
    for (int it = 0; it < 4; it++) {
        int j = it * 32 + (tid >> 3);
        int l8 = tid & 7;
        int srcn = edat[e0 + j].x;
        bf16x8 xv = *(const bf16x8*)(x_bf + (size_t)srcn * 64 + l8 * 8);
        float* mrow = &msg[j][l8 * 8];
        f32x4 m0 = *(const f32x4*)mrow, m1 = *(const f32x4*)(mrow + 4);
#pragma unroll
        for (int k = 0; k < 4; k++) {
            m0[k] = fmaxf(m0[k] + (float)xv[k], 0.f);
            m1[k] = fmaxf(m1[k] + (float)xv[k + 4], 0.f);
        }
        *(f32x4*)mrow = m0;
        *(f32x4*)(mrow + 4) = m1;
    }
    __syncthreads();
    // segment reduce over this block's edge window
    int nfirst = edat[e0].y, nlast = edat[e0 + 127].y;
    int c = tid & 63;
    for (int n = nfirst + (tid >> 6); n <= nlast; n += 4) {
        int rs = row_ptr[n], re = row_ptr[n + 1];
        int a = rs > e0 ? rs : e0;
        int b = re < e0 + 128 ? re : e0 + 128;
        if (a >= b) continue;
        float sum = 0.f;
        for (int jj = a; jj < b; jj++) sum += msg[jj - e0][c];
        float* addr = h + (size_t)n * 64 + c;
        if (rs >= e0 && re <= e0 + 128) *addr += sum;  // sole owner
        else atomicAdd(addr, sum);                     // boundary node
    }
}

// ---- fused MLP: t = h@w1+b1 -> BN1 -> relu -> @w2+b2 -> BN2 [-> relu] ----
// One kernel, two grid barriers. 512 blocks = exactly 2/CU (balanced; R7
// showed non-multiple-of-256 grids straggle at the barrier). Contended
// atomics sharded x8 (R8: -64us): stats are 8 shadow copies summed at use;
// barrier is 8 counters on separate 128B lines, spinners poll the sum.
// RELEASE arrive + RELAXED spin only (acquire-per-poll invalidates XCD L2
// every iteration -> R4's 60us/barrier). t in swizzled LDS; h2 in VGPRs
// across the BN2 barrier; phase 3 goes through LDS for coalesced stores.

__device__ __forceinline__ int swz_idx(int row, int col) {
    // bf16 element index with byte-XOR swizzle; keeps 16B alignment for b128 ops
    return ((row * 128 + col * 2) ^ ((row & 7) << 4)) >> 1;
}

__device__ __forceinline__ void gbar(int* bars, int target) {
    __syncthreads();
    if (threadIdx.x == 0) {
        __hip_atomic_fetch_add(bars + (blockIdx.x & 7) * 32, 1,
                               __ATOMIC_RELEASE, __HIP_MEMORY_SCOPE_AGENT);
        int s;
        do {
            s = 0;
#pragma unroll
            for (int j = 0; j < 8; j++)
                s += __hip_atomic_load(bars + j * 32, __ATOMIC_RELAXED,
                                       __HIP_MEMORY_SCOPE_AGENT);
            if (s < target) __builtin_amdgcn_s_sleep(16);
        } while (s < target);
    }
    __syncthreads();
}

template <int LAST>
__global__ __launch_bounds__(256, 2) void k_mlp(
    const float* __restrict__ h, const bf16_t* __restrict__ w1frag_l,
    const bf16_t* __restrict__ w2frag_l, const float* __restrict__ b1_l,
    const float* __restrict__ g1, const float* __restrict__ bb1,
    const float* __restrict__ b2_l, const float* __restrict__ g2,
    const float* __restrict__ bb2, float* __restrict__ stats1,
    float* __restrict__ stats2, int* __restrict__ bars, float* __restrict__ hout,
    bf16_t* __restrict__ x_bf, float* __restrict__ out) {
    // sbuf: phases 1-2 = two 128x64 bf16 t-tiles (swizzled);
    // phase 3 = one [128][68] f32 tile (h2 transpose for coalesced stores).
    __shared__ __align__(16) char sbuf[34816];
    __shared__ float sred[128];
    __shared__ float cf[128];
    bf16_t* tls0 = (bf16_t*)sbuf;
    bf16_t* tls1 = (bf16_t*)(sbuf + 16384);
    float (*fls)[68] = (float(*)[68])sbuf;
    int tid = threadIdx.x, wave = tid >> 6, lane = tid & 63, quad = lane >> 4, l16 = lane & 15;
    int shard = (blockIdx.x & 7) * 128;

    bf16x8 bfrag[2][4];
    const bf16x8* wf1 = (const bf16x8*)w1frag_l;
#pragma unroll
    for (int s = 0; s < 2; s++)
#pragma unroll
        for (int nt = 0; nt < 4; nt++) bfrag[s][nt] = wf1[(s * 4 + nt) * 64 + lane];

    if (tid < 128) sred[tid] = 0.f;
    __syncthreads();

    // ---- phase 1: t-tiles + BN1 stats ----
#pragma unroll
    for (int ti = 0; ti < 2; ti++) {
        int tile = blockIdx.x + ti * NBLK_MLP;
        if (tile >= NTILE) continue;
        bf16_t* tl = ti ? tls1 : tls0;
        int r0 = tile * 128;
        f32x4 acc[2][4];
#pragma unroll
        for (int rt = 0; rt < 2; rt++)
#pragma unroll
            for (int nt = 0; nt < 4; nt++) acc[rt][nt] = (f32x4)(0.f);
#pragma unroll
        for (int rt = 0; rt < 2; rt++) {
            int n = r0 + wave * 32 + rt * 16 + l16;
            bool valid = n < N_NODES;
#pragma unroll
            for (int s = 0; s < 2; s++) {
                bf16x8 a;
                if (valid) {
                    const float* hp = h + (size_t)n * 64 + s * 32 + quad * 8;
                    f32x4 v0 = *(const f32x4*)hp, v1 = *(const f32x4*)(hp + 4);
#pragma unroll
                    for (int i = 0; i < 4; i++) { a[i] = (bf16_t)v0[i]; a[i + 4] = (bf16_t)v1[i]; }
                } else {
#pragma unroll
                    for (int i = 0; i < 8; i++) a[i] = (bf16_t)0.f;
                }
#pragma unroll
                for (int nt = 0; nt < 4; nt++)
                    acc[rt][nt] = __builtin_amdgcn_mfma_f32_16x16x32_bf16(a, bfrag[s][nt],
                                                                         acc[rt][nt], 0, 0, 0);
            }
        }
#pragma unroll
        for (int nt = 0; nt < 4; nt++) {
            int col = nt * 16 + l16;
            float bias = b1_l[col];
            float s1 = 0.f, s2 = 0.f;
#pragma unroll
            for (int rt = 0; rt < 2; rt++)
#pragma unroll
                for (int r = 0; r < 4; r++) {
                    int rloc = wave * 32 + rt * 16 + quad * 4 + r;
                    int n = r0 + rloc;
                    if (n < N_NODES) {
                        float v = acc[rt][nt][r] + bias;
                        tl[swz_idx(rloc, col)] = (bf16_t)v;
                        s1 += v; s2 += v * v;
                    } else {
                        tl[swz_idx(rloc, col)] = (bf16_t)0.f;
                    }
                }
            s1 += __shfl_xor(s1, 16); s1 += __shfl_xor(s1, 32);
            s2 += __shfl_xor(s2, 16); s2 += __shfl_xor(s2, 32);
            if (quad == 0) { atomicAdd(&sred[col], s1); atomicAdd(&sred[64 + col], s2); }
        }
    }
    __syncthreads();
    if (tid < 128) atomicAdd(&stats1[shard + tid], sred[tid]);
    gbar(bars, NBLK_MLP);

    // ---- phase 2: BN1 coefs (sum 8 shards), second GEMM (h2 in registers) ----
    if (tid < 128) sred[tid] = 0.f;
    if (tid < 64) {
        float sa = 0.f, sb = 0.f;
#pragma unroll
        for (int j = 0; j < 8; j++) {
            sa += __hip_atomic_load(stats1 + j * 128 + tid, __ATOMIC_RELAXED,
                                    __HIP_MEMORY_SCOPE_AGENT);
            sb += __hip_atomic_load(stats1 + j * 128 + 64 + tid, __ATOMIC_RELAXED,
                                    __HIP_MEMORY_SCOPE_AGENT);
        }
        float mean = sa / (float)N_NODES;
        float var = sb / (float)N_NODES - mean * mean;
        float a = g1[tid] * rsqrtf(var + EPS_BN);
        cf[tid] = a;
        cf[64 + tid] = bb1[tid] - mean * a;
    }
    __syncthreads();

    bf16x8 b2frag[2][4];
    const bf16x8* wf2 = (const bf16x8*)w2frag_l;
#pragma unroll
    for (int s = 0; s < 2; s++)
#pragma unroll
        for (int nt = 0; nt < 4; nt++) b2frag[s][nt] = wf2[(s * 4 + nt) * 64 + lane];

    f32x4 acc2[2][2][4];
#pragma unroll
    for (int ti = 0; ti < 2; ti++)
#pragma unroll
        for (int rt = 0; rt < 2; rt++)
#pragma unroll
            for (int nt = 0; nt < 4; nt++) acc2[ti][rt][nt] = (f32x4)(0.f);

#pragma unroll
    for (int ti = 0; ti < 2; ti++) {
        int tile = blockIdx.x + ti * NBLK_MLP;
        if (tile >= NTILE) continue;
        bf16_t* tl = ti ? tls1 : tls0;
#pragma unroll
        for (int rt = 0; rt < 2; rt++) {
            int rloc = wave * 32 + rt * 16 + l16;
#pragma unroll
            for (int s = 0; s < 2; s++) {
                int k0 = s * 32 + quad * 8;
                bf16x8 tv = *(const bf16x8*)&tl[swz_idx(rloc, k0)];
                bf16x8 a;
#pragma unroll
                for (int i = 0; i < 8; i++) {
                    float y = (float)tv[i] * cf[k0 + i] + cf[64 + k0 + i];
                    a[i] = (bf16_t)fmaxf(y, 0.f);
                }
#pragma unroll
                for (int nt = 0; nt < 4; nt++)
                    acc2[ti][rt][nt] = __builtin_amdgcn_mfma_f32_16x16x32_bf16(
                        a, b2frag[s][nt], acc2[ti][rt][nt], 0, 0, 0);
            }
        }
    }

    // BN2 stats from register-resident h2
#pragma unroll
    for (int nt = 0; nt < 4; nt++) {
        int col = nt * 16 + l16;
        float bias = b2_l[col];
        float s1 = 0.f, s2 = 0.f;
#pragma unroll
        for (int ti = 0; ti < 2; ti++) {
            int tile = blockIdx.x + ti * NBLK_MLP;
            if (tile >= NTILE) continue;
            int r0 = tile * 128;
#pragma unroll
            for (int rt = 0; rt < 2; rt++)
#pragma unroll
                for (int r = 0; r < 4; r++) {
                    int n = r0 + wave * 32 + rt * 16 + quad * 4 + r;
                    if (n < N_NODES) {
                        float v = acc2[ti][rt][nt][r] + bias;
                        s1 += v; s2 += v * v;
                    }
                }
        }
        s1 += __shfl_xor(s1, 16); s1 += __shfl_xor(s1, 32);
        s2 += __shfl_xor(s2, 16); s2 += __shfl_xor(s2, 32);
        if (quad == 0) { atomicAdd(&sred[col], s1); atomicAdd(&sred[64 + col], s2); }
    }
    __syncthreads();
    if (tid < 128) atomicAdd(&stats2[shard + tid], sred[tid]);
    gbar(bars, 2 * NBLK_MLP);

    // ---- phase 3: BN2 coefs (sum 8 shards), h2 -> LDS -> coalesced stores ----
    if (tid < 64) {
        float sa = 0.f, sb = 0.f;
#pragma unroll
        for (int j = 0; j < 8; j++) {
            sa += __hip_atomic_load(stats2 + j * 128 + tid, __ATOMIC_RELAXED,
                                    __HIP_MEMORY_SCOPE_AGENT);
            sb += __hip_atomic_load(stats2 + j * 128 + 64 + tid, __ATOMIC_RELAXED,
                                    __HIP_MEMORY_SCOPE_AGENT);
        }
        float mean = sa / (float)N_NODES;
        float var = sb / (float)N_NODES - mean * mean;
        float a = g2[tid] * rsqrtf(var + EPS_BN);
        cf[tid] = a;
        cf[64 + tid] = bb2[tid] - mean * a;
    }
#pragma unroll
    for (int ti = 0; ti < 2; ti++) {
        int tile = blockIdx.x + ti * NBLK_MLP;
        if (tile >= NTILE) continue;   // block-uniform: all threads agree
        __syncthreads();               // fls free (tls dead / prev tile done); cf visible
        int r0 = tile * 128;
#pragma unroll
        for (int nt = 0; nt < 4; nt++) {
            int col = nt * 16 + l16;
            float bias = b2_l[col];
#pragma unroll
            for (int rt = 0; rt < 2; rt++)
#pragma unroll
                for (int r = 0; r < 4; r++)
                    fls[wave * 32 + rt * 16 + quad * 4 + r][col] = acc2[ti][rt][nt][r] + bias;
        }
        __syncthreads();
#pragma unroll
        for (int pass = 0; pass < 4; pass++) {
            int rloc = pass * 32 + (tid >> 3);
            int n = r0 + rloc;
            if (n >= N_NODES) continue;
            int c0 = (tid & 7) * 8;
            f32x4 v0 = *(const f32x4*)&fls[rloc][c0];
            f32x4 v1 = *(const f32x4*)&fls[rloc][c0 + 4];
            f32x4 y0, y1;
#pragma unroll
            for (int k = 0; k < 4; k++) {
                y0[k] = v0[k] * cf[c0 + k] + cf[64 + c0 + k];
                y1[k] = v1[k] * cf[c0 + 4 + k] + cf[64 + c0 + 4 + k];
            }
            if (LAST) {
                *(f32x4*)(out + (size_t)n * 64 + c0) = y0;
                *(f32x4*)(out + (size_t)n * 64 + c0 + 4) = y1;
            } else {
                bf16x8 o;
#pragma unroll
                for (int k = 0; k < 4; k++) {
                    y0[k] = fmaxf(y0[k], 0.f);
                    y1[k] = fmaxf(y1[k], 0.f);
                    o[k] = (bf16_t)y0[k]; o[k + 4] = (bf16_t)y1[k];
                }
                *(f32x4*)(hout + (size_t)n * 64 + c0) = y0;
                *(f32x4*)(hout + (size_t)n * 64 + c0 + 4) = y1;
                *(bf16x8*)(x_bf + (size_t)n * 64 + c0) = o;
            }
        }
    }
}

// ---------------- host ----------------

extern "C" void kernel_launch(void* const* d_in, const int* in_sizes, int n_in,
                              void* d_out, int out_size, void* d_ws, size_t ws_size,
                              hipStream_t stream) {
    const float* x_in   = (const float*)d_in[0];
    const float* pe     = (const float*)d_in[1];
    const float* Lam    = (const float*)d_in[2];
    const float* eattr  = (const float*)d_in[3];
    const float* phi_w1 = (const float*)d_in[4];
    const float* phi_b1 = (const float*)d_in[5];
    const float* phi_w2 = (const float*)d_in[6];
    const float* phi_b2 = (const float*)d_in[7];
    const float* enc_w  = (const float*)d_in[8];
    const float* enc_b  = (const float*)d_in[9];
    const float* lin_w  = (const float*)d_in[10];
    const float* lin_b  = (const float*)d_in[11];
    const float* mlp_w1 = (const float*)d_in[12];
    const float* mlp_b1 = (const float*)d_in[13];
    const float* bn1_g  = (const float*)d_in[14];
    const float* bn1_b  = (const float*)d_in[15];
    const float* mlp_w2 = (const float*)d_in[16];
    const float* mlp_b2 = (const float*)d_in[17];
    const float* bn2_g  = (const float*)d_in[18];
    const float* bn2_b  = (const float*)d_in[19];
    const int* edge_index = (const int*)d_in[20];
    const int* batch      = (const int*)d_in[21];
    float* out = (float*)d_out;

    char* ws = (char*)d_ws;
    size_t off = 0;
    auto alloc = [&](size_t bytes) -> void* {
        void* p = ws + off;
        off += (bytes + 255) & ~(size_t)255;
        return p;
    };
    bf16_t* feat      = (bf16_t*)alloc((size_t)N_EDGES * 128 * 2);
    int4* edat        = (int4*)alloc((size_t)N_EDGES * 16);
    int* row_ptr      = (int*)alloc((size_t)(N_NODES + 1) * 4);
    int* blk          = (int*)alloc(128 * 4);
    // zero-init region (one memset): counts | cursor | stats(8-shard) | bar(8-shard)
    int* counts       = (int*)alloc((size_t)N_NODES * 4);
    int* cursor       = (int*)alloc((size_t)N_NODES * 4);
    float* stats      = (float*)alloc((size_t)NL * 2048 * 4); // per layer: s1[8][128], s2[8][128]
    int* bar          = (int*)alloc((size_t)NL * 256 * 4);    // per layer: 8 counters, 128B apart
    size_t zbytes     = (char*)(bar + NL * 256) - (char*)counts;
    float* h          = (float*)alloc((size_t)N_NODES * 64 * 4);
    bf16_t* x_bf      = (bf16_t*)alloc((size_t)N_NODES * 64 * 2);
    bf16_t* w_all     = (bf16_t*)alloc((size_t)NL * NB * QM * 2);
    bf16_t* wcat_frag = (bf16_t*)alloc((size_t)NL * 8192 * 2);
    bf16_t* w1frag    = (bf16_t*)alloc((size_t)NL * 4096 * 2);
    bf16_t* w2frag    = (bf16_t*)alloc((size_t)NL * 4096 * 2);
    float* cvec       = (float*)alloc((size_t)NL * 64 * 4);

    // ---- one-time setup ----
    hipMemsetAsync(counts, 0, zbytes, stream);
    k_count<<<3125, 256, 0, stream>>>(edge_index + N_EDGES, counts);
    k_scan1<<<98, 1024, 0, stream>>>(counts, row_ptr, blk);
    k_scan2<<<1, 128, 0, stream>>>(blk);
    k_scan3<<<98, 1024, 0, stream>>>(blk, row_ptr);
    k_build<<<50000, 256, 0, stream>>>(edge_index, batch, row_ptr, cursor, edat,
                                       pe, eattr, feat);
    k_phi<<<50, 256, 0, stream>>>(Lam, phi_w1, phi_b1, phi_w2, phi_b2, w_all);
    k_prep<<<NL, 256, 0, stream>>>(enc_w, enc_b, lin_w, lin_b, mlp_w1, mlp_w2,
                                   wcat_frag, w1frag, w2frag, cvec);

    // ---- layers ----
    k_hinit0<<<3125, 256, 0, stream>>>(x_in, pe, x_bf, h, out + (size_t)N_NODES * 64);
    for (int l = 0; l < NL; l++) {
        float* s1 = stats + (size_t)l * 2048;
        float* s2 = stats + (size_t)l * 2048 + 1024;
        int* bl = bar + (size_t)l * 256;
        k_edge<<<6250, 256, 0, stream>>>(feat, edat, row_ptr,
                                         w_all + (size_t)l * NB * QM,
                                         wcat_frag + (size_t)l * 8192,
                                         cvec + (size_t)l * 64, x_bf, h);
        if (l < NL - 1)
            k_mlp<0><<<NBLK_MLP, 256, 0, stream>>>(
                h, w1frag + (size_t)l * 4096, w2frag + (size_t)l * 4096,
                mlp_b1 + l * 64, bn1_g + l * 64, bn1_b + l * 64,
                mlp_b2 + l * 64, bn2_g + l * 64, bn2_b + l * 64,
                s1, s2, bl, h, x_bf, (float*)nullptr);
        else
            k_mlp<1><<<NBLK_MLP, 256, 0, stream>>>(
                h, w1frag + (size_t)l * 4096, w2frag + (size_t)l * 4096,
                mlp_b1 + l * 64, bn1_g + l * 64, bn1_b + l * 64,
                mlp_b2 + l * 64, bn2_g + l * 64, bn2_b + l * 64,
                s1, s2, bl, h, x_bf, out);
    }
}

// Round 16
// 1074.642 us; speedup vs baseline: 1.1960x; 1.0098x over previous
//
#include <hip/hip_runtime.h>

#define N_NODES 100000
#define N_EDGES 800000
#define NB 100
#define NL 4
#define QM 32
#define EPS_BN 1e-5f
#define NTILE 782      // ceil(N_NODES / 128)
#define NBLK_MLP 512   // 2 tiles/block, exactly 2 blocks/CU -> balanced grid barrier

typedef __bf16 bf16_t;
typedef __bf16 bf16x8 __attribute__((ext_vector_type(8)));
typedef __bf16 bf16x4 __attribute__((ext_vector_type(4)));
typedef __bf16 bf16x2 __attribute__((ext_vector_type(2)));
typedef float f32x4 __attribute__((ext_vector_type(4)));
typedef unsigned int u32;
typedef unsigned long long u64;

// ---------------- setup: counting sort by dst ----------------

// counts edges per dst AND records each edge's rank within its dst bucket
// (the atomic's return value). k_build then needs NO atomics: R13 showed its
// 800K cursor atomics bounced ~100MB of lines across XCD L2s (FETCH excess).
__global__ void k_count(const int* __restrict__ dst, int* __restrict__ counts,
                        int* __restrict__ rank) {
    int e = blockIdx.x * 256 + threadIdx.x;
    if (e < N_EDGES) rank[e] = atomicAdd(&counts[dst[e]], 1);
}

__global__ void k_scan1(const int* __restrict__ counts, int* __restrict__ row_ptr,
                        int* __restrict__ blk) {
    __shared__ int s[1024];
    int i = blockIdx.x * 1024 + threadIdx.x;
    int v = (i < N_NODES) ? counts[i] : 0;
    s[threadIdx.x] = v;
    __syncthreads();
    for (int off = 1; off < 1024; off <<= 1) {
        int u = (threadIdx.x >= off) ? s[threadIdx.x - off] : 0;
        __syncthreads();
        s[threadIdx.x] += u;
        __syncthreads();
    }
    if (i < N_NODES) row_ptr[i] = s[threadIdx.x] - v;   // block-local exclusive
    if (threadIdx.x == 1023) blk[blockIdx.x] = s[1023]; // block total
}

__global__ void k_scan2(int* __restrict__ blk) { // exclusive scan of 98 block totals
    __shared__ int s[128];
    int t = threadIdx.x;
    int v = (t < 98) ? blk[t] : 0;
    s[t] = v;
    __syncthreads();
    for (int off = 1; off < 128; off <<= 1) {
        int u = (t >= off) ? s[t - off] : 0;
        __syncthreads();
        s[t] += u;
        __syncthreads();
    }
    if (t < 98) blk[t] = s[t] - v;
}

__global__ void k_scan3(const int* __restrict__ blk, int* __restrict__ row_ptr) {
    int i = blockIdx.x * 1024 + threadIdx.x;
    if (i < N_NODES) row_ptr[i] += blk[blockIdx.x];
    if (i == 0) row_ptr[N_NODES] = N_EDGES;
}

// merged scatter+permute, 16 lanes per edge in ORIGINAL edge order, ZERO
// atomics (pos = row_ptr[dst] + rank[e], both L3-resident broadcast loads).
// ea read is coalesced streaming; pe gathers are L3-resident; feat written
// as two full 128B segments per edge (cross-lane z repack via two 64-bit
// shuffles); edat 16B scatter remains.
__global__ void k_build(const int* __restrict__ ei, const int* __restrict__ batch,
                        const int* __restrict__ row_ptr, const int* __restrict__ rank,
                        int4* __restrict__ edat, const float* __restrict__ pe,
                        const float* __restrict__ ea, bf16_t* __restrict__ feat) {
    int t = blockIdx.x * 256 + threadIdx.x;
    int g = t >> 4, k = t & 15;          // one 16-lane group per edge; grid exact
    int lane = threadIdx.x & 63;
    int base = lane & ~15;               // first lane of this group within the wave
    int s = ei[g], d = ei[N_EDGES + g];  // same addr across group -> broadcast load
    int pos = row_ptr[d] + rank[g];      // no atomics (rank precomputed in k_count)
    if (k == 0) edat[pos] = make_int4(s, d, batch[s], g);
    f32x4 av = *(const f32x4*)(ea + (size_t)g * 64 + k * 4);   // coalesced
    f32x4 sv = *(const f32x4*)(pe + (size_t)s * 64 + k * 4);   // L3-hit gather
    f32x4 dv = *(const f32x4*)(pe + (size_t)d * 64 + k * 4);
    bf16x4 ao;
#pragma unroll
    for (int i = 0; i < 4; i++) ao[i] = (bf16_t)av[i];
    bf16x2 re, im;
    re[0] = (bf16_t)(sv[0] * dv[0] + sv[1] * dv[1]);
    re[1] = (bf16_t)(sv[2] * dv[2] + sv[3] * dv[3]);
    im[0] = (bf16_t)(sv[1] * dv[0] - sv[0] * dv[1]);
    im[1] = (bf16_t)(sv[3] * dv[2] - sv[2] * dv[3]);
    // repack z across the group: lane k collects z-row elements 4k..4k+3
    // (re for k<8, im for k>=8) from lanes 2*(k&7) and 2*(k&7)+1.
    u64 z = ((u64)(*(u32*)&im) << 32) | (u64)(*(u32*)&re);
    u64 za = __shfl(z, base + 2 * (k & 7));
    u64 zb = __shfl(z, base + 2 * (k & 7) + 1);
    u32 lo = (k < 8) ? (u32)za : (u32)(za >> 32);
    u32 hi = (k < 8) ? (u32)zb : (u32)(zb >> 32);
    bf16_t* f = feat + (size_t)pos * 128;
    uint2 zw = make_uint2(lo, hi);
    *(uint2*)(f + 4 * k) = zw;            // bytes 0..127: full segment per group
    *(bf16x4*)(f + 64 + 4 * k) = ao;      // bytes 128..255: full segment per group
}

// ---------------- weight prep ----------------

__global__ void k_phi(const float* __restrict__ Lam, const float* __restrict__ w1,
                      const float* __restrict__ b1, const float* __restrict__ w2,
                      const float* __restrict__ b2, bf16_t* __restrict__ w_all) {
    int idx = blockIdx.x * 256 + threadIdx.x;
    if (idx >= NL * NB * QM) return;
    int l = idx / (NB * QM);
    int rem = idx % (NB * QM);
    float lam = Lam[rem];
    float acc = b2[l];
    for (int i = 0; i < 16; i++) {
        float h = lam * w1[l * 16 + i] + b1[l * 16 + i];
        acc += fmaxf(h, 0.f) * w2[l * 16 + i];
    }
    w_all[idx] = (bf16_t)acc;
}

__global__ void k_prep(const float* __restrict__ enc_w, const float* __restrict__ enc_b,
                       const float* __restrict__ lin_w, const float* __restrict__ lin_b,
                       const float* __restrict__ mlp_w1, const float* __restrict__ mlp_w2,
                       bf16_t* __restrict__ wcat_frag, bf16_t* __restrict__ w1frag,
                       bf16_t* __restrict__ w2frag, float* __restrict__ cvec) {
    __shared__ float lds[128][64];
    int l = blockIdx.x, tid = threadIdx.x;
    const float* ew = enc_w + l * 64 * 64;
    const float* lw = lin_w + l * 64 * 64;
    for (int idx = tid; idx < 64 * 64; idx += 256) {
        int r = idx >> 6, c = idx & 63;
        float acc = 0.f;
        for (int k = 0; k < 64; k++) acc += ew[r * 64 + k] * lw[k * 64 + c];
        lds[r][c] = acc;
        lds[64 + r][c] = lw[r * 64 + c];
    }
    if (tid < 64) {
        float acc = lin_b[l * 64 + tid];
        for (int k = 0; k < 64; k++) acc += enc_b[l * 64 + k] * lw[k * 64 + tid];
        cvec[l * 64 + tid] = acc;
    }
    __syncthreads();
    for (int idx = tid; idx < 16 * 512; idx += 256) {
        int sn = idx >> 9, lane = (idx >> 3) & 63, j = idx & 7;
        int s = sn >> 2, nt = sn & 3;
        int row = 32 * s + (lane >> 4) * 8 + j;
        int col = 16 * nt + (lane & 15);
        wcat_frag[l * 8192 + idx] = (bf16_t)lds[row][col];
    }
    for (int idx = tid; idx < 8 * 512; idx += 256) {
        int sn = idx >> 9, lane = (idx >> 3) & 63, j = idx & 7;
        int s = sn >> 2, nt = sn & 3;
        int row = 32 * s + (lane >> 4) * 8 + j; // k index
        int col = 16 * nt + (lane & 15);
        w1frag[l * 4096 + idx] = (bf16_t)mlp_w1[(l * 64 + row) * 64 + col];
        w2frag[l * 4096 + idx] = (bf16_t)mlp_w2[(l * 64 + row) * 64 + col];
    }
}

// ---------------- per-layer kernels ----------------

// layer 0 init: x_bf = bf16(x), h = x; also pe passthrough to out (replaces memcpy)
__global__ void k_hinit0(const float* __restrict__ x, const float* __restrict__ pe,
                         bf16_t* __restrict__ x_bf, float* __restrict__ h,
                         float* __restrict__ out_pe) {
    size_t i = ((size_t)blockIdx.x * 256 + threadIdx.x) * 8;
    f32x4 a = *(const f32x4*)(x + i), b = *(const f32x4*)(x + i + 4);
    *(f32x4*)(h + i) = a;
    *(f32x4*)(h + i + 4) = b;
    bf16x8 o;
#pragma unroll
    for (int k = 0; k < 4; k++) { o[k] = (bf16_t)a[k]; o[k + 4] = (bf16_t)b[k]; }
    *(bf16x8*)(x_bf + i) = o;
    f32x4 p0 = *(const f32x4*)(pe + i), p1 = *(const f32x4*)(pe + i + 4);
    *(f32x4*)(out_pe + i) = p0;
    *(f32x4*)(out_pe + i + 4) = p1;
}

// 128 dst-sorted edges per block: msg = relu(x[src] + feat @ Wcat + cvec),
// then in-block segment sum into h (h pre-initialized to x).
__global__ void k_edge(const bf16_t* __restrict__ feat, const int4* __restrict__ edat,
                       const int* __restrict__ row_ptr, const bf16_t* __restrict__ w_l,
                       const bf16_t* __restrict__ wcat_l, const float* __restrict__ cvec_l,
                       const bf16_t* __restrict__ x_bf, float* __restrict__ h) {
    __shared__ float msg[128][68];
    int tid = threadIdx.x;
    int wave = tid >> 6, lane = tid & 63;
    int quad = lane >> 4, l16 = lane & 15;
    int e0 = blockIdx.x * 128;

    bf16x8 bfrag[4][4];
    const bf16x8* wf = (const bf16x8*)wcat_l;
#pragma unroll
    for (int s = 0; s < 4; s++)
#pragma unroll
        for (int nt = 0; nt < 4; nt++) bfrag[s][nt] = wf[(s * 4 + nt) * 64 + lane];

    f32x4 acc[2][4];
#pragma unroll
    for (int rt = 0; rt < 2; rt++)
#pragma unroll
        for (int nt = 0; nt < 4; nt++) acc[rt][nt] = (f32x4)(0.f);

    int em[2];
    bf16x8 wch[2];
#pragma unroll
    for (int rt = 0; rt < 2; rt++) {
        em[rt] = e0 + wave * 32 + rt * 16 + l16;
        int eg = edat[em[rt]].z;
        wch[rt] = *(const bf16x8*)(w_l + (size_t)eg * QM + quad * 8);
    }
#pragma unroll
    for (int s = 0; s < 4; s++) {
        bf16x8 afr[2];
#pragma unroll
        for (int rt = 0; rt < 2; rt++) {
            bf16x8 v = *(const bf16x8*)(feat + (size_t)em[rt] * 128 + s * 32 + quad * 8);
            if (s < 2) {
                bf16x8 a;
#pragma unroll
                for (int i = 0; i < 8; i++) a[i] = (bf16_t)((float)v[i] * (float)wch[rt][i]);
                afr[rt] = a;
            } else {
                afr[rt] = v;
            }
        }
#pragma unroll
        for (int rt = 0; rt < 2; rt++)
#pragma unroll
            for (int nt = 0; nt < 4; nt++)
                acc[rt][nt] = __builtin_amdgcn_mfma_f32_16x16x32_bf16(afr[rt], bfrag[s][nt],
                                                                     acc[rt][nt], 0, 0, 0);
    }
    // C layout: row = quad*4 + r, col = lane&15 (per 16x16 tile)
#pragma unroll
    for (int nt = 0; nt < 4; nt++) {
        float cv = cvec_l[nt * 16 + l16];
#pragma unroll
        for (int rt = 0; rt < 2; rt++)
#pragma unroll
            for (int r = 0; r < 4; r++)
                msg[wave * 32 + rt * 16 + quad * 4 + r][nt * 16 + l16] = acc[rt][nt][r] + cv;
    }
    __syncthreads();
    // add x[src] (bf16 row = 128B per 8-lane group), relu
#pragma unroll
    for (int it = 0; it < 4; it++) {
        int j = it * 32 + (tid >> 3);
        int l8 = tid & 7;
        int srcn = edat[e0 + j].x;
        bf16x8 xv = *(const bf16x8*)(x_bf + (size_t)srcn * 64 + l8 * 8);
        float* mrow = &msg[j][l8 * 8];
        f32x4 m0 = *(const f32x4*)mrow, m1 = *(const f32x4*)(mrow + 4);
#pragma unroll
        for (int k = 0; k < 4; k++) {
            m0[k] = fmaxf(m0[k] + (float)xv[k], 0.f);
            m1[k] = fmaxf(m1[k] + (float)xv[k + 4], 0.f);
        }
        *(f32x4*)mrow = m0;
        *(f32x4*)(mrow + 4) = m1;
    }
    __syncthreads();
    // segment reduce over this block's edge window
    int nfirst = edat[e0].y, nlast = edat[e0 + 127].y;
    int c = tid & 63;
    for (int n = nfirst + (tid >> 6); n <= nlast; n += 4) {
        int rs = row_ptr[n], re = row_ptr[n + 1];
        int a = rs > e0 ? rs : e0;
        int b = re < e0 + 128 ? re : e0 + 128;
        if (a >= b) continue;
        float sum = 0.f;
        for (int jj = a; jj < b; jj++) sum += msg[jj - e0][c];
        float* addr = h + (size_t)n * 64 + c;
        if (rs >= e0 && re <= e0 + 128) *addr += sum;  // sole owner
        else atomicAdd(addr, sum);                     // boundary node
    }
}

// ---- fused MLP: t = h@w1+b1 -> BN1 -> relu -> @w2+b2 -> BN2 [-> relu] ----
// One kernel, two grid barriers. 512 blocks = exactly 2/CU (balanced; R7
// showed non-multiple-of-256 grids straggle at the barrier). Contended
// atomics sharded x8 (R8: -64us): stats are 8 shadow copies summed at use;
// barrier is 8 counters on separate 128B lines, spinners poll the sum.
// RELEASE arrive + RELAXED spin only (acquire-per-poll invalidates XCD L2
// every iteration -> R4's 60us/barrier). t in swizzled LDS; h2 in VGPRs
// across the BN2 barrier; phase 3 goes through LDS for coalesced stores.

__device__ __forceinline__ int swz_idx(int row, int col) {
    // bf16 element index with byte-XOR swizzle; keeps 16B alignment for b128 ops
    return ((row * 128 + col * 2) ^ ((row & 7) << 4)) >> 1;
}

__device__ __forceinline__ void gbar(int* bars, int target) {
    __syncthreads();
    if (threadIdx.x == 0) {
        __hip_atomic_fetch_add(bars + (blockIdx.x & 7) * 32, 1,
                               __ATOMIC_RELEASE, __HIP_MEMORY_SCOPE_AGENT);
        int s;
        do {
            s = 0;
#pragma unroll
            for (int j = 0; j < 8; j++)
                s += __hip_atomic_load(bars + j * 32, __ATOMIC_RELAXED,
                                       __HIP_MEMORY_SCOPE_AGENT);
            if (s < target) __builtin_amdgcn_s_sleep(16);
        } while (s < target);
    }
    __syncthreads();
}

template <int LAST>
__global__ __launch_bounds__(256, 2) void k_mlp(
    const float* __restrict__ h, const bf16_t* __restrict__ w1frag_l,
    const bf16_t* __restrict__ w2frag_l, const float* __restrict__ b1_l,
    const float* __restrict__ g1, const float* __restrict__ bb1,
    const float* __restrict__ b2_l, const float* __restrict__ g2,
    const float* __restrict__ bb2, float* __restrict__ stats1,
    float* __restrict__ stats2, int* __restrict__ bars, float* __restrict__ hout,
    bf16_t* __restrict__ x_bf, float* __restrict__ out) {
    // sbuf: phases 1-2 = two 128x64 bf16 t-tiles (swizzled);
    // phase 3 = one [128][68] f32 tile (h2 transpose for coalesced stores).
    __shared__ __align__(16) char sbuf[34816];
    __shared__ float sred[128];
    __shared__ float cf[128];
    bf16_t* tls0 = (bf16_t*)sbuf;
    bf16_t* tls1 = (bf16_t*)(sbuf + 16384);
    float (*fls)[68] = (float(*)[68])sbuf;
    int tid = threadIdx.x, wave = tid >> 6, lane = tid & 63, quad = lane >> 4, l16 = lane & 15;
    int shard = (blockIdx.x & 7) * 128;

    bf16x8 bfrag[2][4];
    const bf16x8* wf1 = (const bf16x8*)w1frag_l;
#pragma unroll
    for (int s = 0; s < 2; s++)
#pragma unroll
        for (int nt = 0; nt < 4; nt++) bfrag[s][nt] = wf1[(s * 4 + nt) * 64 + lane];

    if (tid < 128) sred[tid] = 0.f;
    __syncthreads();

    // ---- phase 1: t-tiles + BN1 stats ----
#pragma unroll
    for (int ti = 0; ti < 2; ti++) {
        int tile = blockIdx.x + ti * NBLK_MLP;
        if (tile >= NTILE) continue;
        bf16_t* tl = ti ? tls1 : tls0;
        int r0 = tile * 128;
        f32x4 acc[2][4];
#pragma unroll
        for (int rt = 0; rt < 2; rt++)
#pragma unroll
            for (int nt = 0; nt < 4; nt++) acc[rt][nt] = (f32x4)(0.f);
#pragma unroll
        for (int rt = 0; rt < 2; rt++) {
            int n = r0 + wave * 32 + rt * 16 + l16;
            bool valid = n < N_NODES;
#pragma unroll
            for (int s = 0; s < 2; s++) {
                bf16x8 a;
                if (valid) {
                    const float* hp = h + (size_t)n * 64 + s * 32 + quad * 8;
                    f32x4 v0 = *(const f32x4*)hp, v1 = *(const f32x4*)(hp + 4);
#pragma unroll
                    for (int i = 0; i < 4; i++) { a[i] = (bf16_t)v0[i]; a[i + 4] = (bf16_t)v1[i]; }
                } else {
#pragma unroll
                    for (int i = 0; i < 8; i++) a[i] = (bf16_t)0.f;
                }
#pragma unroll
                for (int nt = 0; nt < 4; nt++)
                    acc[rt][nt] = __builtin_amdgcn_mfma_f32_16x16x32_bf16(a, bfrag[s][nt],
                                                                         acc[rt][nt], 0, 0, 0);
            }
        }
#pragma unroll
        for (int nt = 0; nt < 4; nt++) {
            int col = nt * 16 + l16;
            float bias = b1_l[col];
            float s1 = 0.f, s2 = 0.f;
#pragma unroll
            for (int rt = 0; rt < 2; rt++)
#pragma unroll
                for (int r = 0; r < 4; r++) {
                    int rloc = wave * 32 + rt * 16 + quad * 4 + r;
                    int n = r0 + rloc;
                    if (n < N_NODES) {
                        float v = acc[rt][nt][r] + bias;
                        tl[swz_idx(rloc, col)] = (bf16_t)v;
                        s1 += v; s2 += v * v;
                    } else {
                        tl[swz_idx(rloc, col)] = (bf16_t)0.f;
                    }
                }
            s1 += __shfl_xor(s1, 16); s1 += __shfl_xor(s1, 32);
            s2 += __shfl_xor(s2, 16); s2 += __shfl_xor(s2, 32);
            if (quad == 0) { atomicAdd(&sred[col], s1); atomicAdd(&sred[64 + col], s2); }
        }
    }
    __syncthreads();
    if (tid < 128) atomicAdd(&stats1[shard + tid], sred[tid]);
    gbar(bars, NBLK_MLP);

    // ---- phase 2: BN1 coefs (sum 8 shards), second GEMM (h2 in registers) ----
    if (tid < 128) sred[tid] = 0.f;
    if (tid < 64) {
        float sa = 0.f, sb = 0.f;
#pragma unroll
        for (int j = 0; j < 8; j++) {
            sa += __hip_atomic_load(stats1 + j * 128 + tid, __ATOMIC_RELAXED,
                                    __HIP_MEMORY_SCOPE_AGENT);
            sb += __hip_atomic_load(stats1 + j * 128 + 64 + tid, __ATOMIC_RELAXED,
                                    __HIP_MEMORY_SCOPE_AGENT);
        }
        float mean = sa / (float)N_NODES;
        float var = sb / (float)N_NODES - mean * mean;
        float a = g1[tid] * rsqrtf(var + EPS_BN);
        cf[tid] = a;
        cf[64 + tid] = bb1[tid] - mean * a;
    }
    __syncthreads();

    bf16x8 b2frag[2][4];
    const bf16x8* wf2 = (const bf16x8*)w2frag_l;
#pragma unroll
    for (int s = 0; s < 2; s++)
#pragma unroll
        for (int nt = 0; nt < 4; nt++) b2frag[s][nt] = wf2[(s * 4 + nt) * 64 + lane];

    f32x4 acc2[2][2][4];
#pragma unroll
    for (int ti = 0; ti < 2; ti++)
#pragma unroll
        for (int rt = 0; rt < 2; rt++)
#pragma unroll
            for (int nt = 0; nt < 4; nt++) acc2[ti][rt][nt] = (f32x4)(0.f);

#pragma unroll
    for (int ti = 0; ti < 2; ti++) {
        int tile = blockIdx.x + ti * NBLK_MLP;
        if (tile >= NTILE) continue;
        bf16_t* tl = ti ? tls1 : tls0;
#pragma unroll
        for (int rt = 0; rt < 2; rt++) {
            int rloc = wave * 32 + rt * 16 + l16;
#pragma unroll
            for (int s = 0; s < 2; s++) {
                int k0 = s * 32 + quad * 8;
                bf16x8 tv = *(const bf16x8*)&tl[swz_idx(rloc, k0)];
                bf16x8 a;
#pragma unroll
                for (int i = 0; i < 8; i++) {
                    float y = (float)tv[i] * cf[k0 + i] + cf[64 + k0 + i];
                    a[i] = (bf16_t)fmaxf(y, 0.f);
                }
#pragma unroll
                for (int nt = 0; nt < 4; nt++)
                    acc2[ti][rt][nt] = __builtin_amdgcn_mfma_f32_16x16x32_bf16(
                        a, b2frag[s][nt], acc2[ti][rt][nt], 0, 0, 0);
            }
        }
    }

    // BN2 stats from register-resident h2
#pragma unroll
    for (int nt = 0; nt < 4; nt++) {
        int col = nt * 16 + l16;
        float bias = b2_l[col];
        float s1 = 0.f, s2 = 0.f;
#pragma unroll
        for (int ti = 0; ti < 2; ti++) {
            int tile = blockIdx.x + ti * NBLK_MLP;
            if (tile >= NTILE) continue;
            int r0 = tile * 128;
#pragma unroll
            for (int rt = 0; rt < 2; rt++)
#pragma unroll
                for (int r = 0; r < 4; r++) {
                    int n = r0 + wave * 32 + rt * 16 + quad * 4 + r;
                    if (n < N_NODES) {
                        float v = acc2[ti][rt][nt][r] + bias;
                        s1 += v; s2 += v * v;
                    }
                }
        }
        s1 += __shfl_xor(s1, 16); s1 += __shfl_xor(s1, 32);
        s2 += __shfl_xor(s2, 16); s2 += __shfl_xor(s2, 32);
        if (quad == 0) { atomicAdd(&sred[col], s1); atomicAdd(&sred[64 + col], s2); }
    }
    __syncthreads();
    if (tid < 128) atomicAdd(&stats2[shard + tid], sred[tid]);
    gbar(bars, 2 * NBLK_MLP);

    // ---- phase 3: BN2 coefs (sum 8 shards), h2 -> LDS -> coalesced stores ----
    if (tid < 64) {
        float sa = 0.f, sb = 0.f;
#pragma unroll
        for (int j = 0; j < 8; j++) {
            sa += __hip_atomic_load(stats2 + j * 128 + tid, __ATOMIC_RELAXED,
                                    __HIP_MEMORY_SCOPE_AGENT);
            sb += __hip_atomic_load(stats2 + j * 128 + 64 + tid, __ATOMIC_RELAXED,
                                    __HIP_MEMORY_SCOPE_AGENT);
        }
        float mean = sa / (float)N_NODES;
        float var = sb / (float)N_NODES - mean * mean;
        float a = g2[tid] * rsqrtf(var + EPS_BN);
        cf[tid] = a;
        cf[64 + tid] = bb2[tid] - mean * a;
    }
#pragma unroll
    for (int ti = 0; ti < 2; ti++) {
        int tile = blockIdx.x + ti * NBLK_MLP;
        if (tile >= NTILE) continue;   // block-uniform: all threads agree
        __syncthreads();               // fls free (tls dead / prev tile done); cf visible
        int r0 = tile * 128;
#pragma unroll
        for (int nt = 0; nt < 4; nt++) {
            int col = nt * 16 + l16;
            float bias = b2_l[col];
#pragma unroll
            for (int rt = 0; rt < 2; rt++)
#pragma unroll
                for (int r = 0; r < 4; r++)
                    fls[wave * 32 + rt * 16 + quad * 4 + r][col] = acc2[ti][rt][nt][r] + bias;
        }
        __syncthreads();
#pragma unroll
        for (int pass = 0; pass < 4; pass++) {
            int rloc = pass * 32 + (tid >> 3);
            int n = r0 + rloc;
            if (n >= N_NODES) continue;
            int c0 = (tid & 7) * 8;
            f32x4 v0 = *(const f32x4*)&fls[rloc][c0];
            f32x4 v1 = *(const f32x4*)&fls[rloc][c0 + 4];
            f32x4 y0, y1;
#pragma unroll
            for (int k = 0; k < 4; k++) {
                y0[k] = v0[k] * cf[c0 + k] + cf[64 + c0 + k];
                y1[k] = v1[k] * cf[c0 + 4 + k] + cf[64 + c0 + 4 + k];
            }
            if (LAST) {
                *(f32x4*)(out + (size_t)n * 64 + c0) = y0;
                *(f32x4*)(out + (size_t)n * 64 + c0 + 4) = y1;
            } else {
                bf16x8 o;
#pragma unroll
                for (int k = 0; k < 4; k++) {
                    y0[k] = fmaxf(y0[k], 0.f);
                    y1[k] = fmaxf(y1[k], 0.f);
                    o[k] = (bf16_t)y0[k]; o[k + 4] = (bf16_t)y1[k];
                }
                *(f32x4*)(hout + (size_t)n * 64 + c0) = y0;
                *(f32x4*)(hout + (size_t)n * 64 + c0 + 4) = y1;
                *(bf16x8*)(x_bf + (size_t)n * 64 + c0) = o;
            }
        }
    }
}

// ---------------- host ----------------

extern "C" void kernel_launch(void* const* d_in, const int* in_sizes, int n_in,
                              void* d_out, int out_size, void* d_ws, size_t ws_size,
                              hipStream_t stream) {
    const float* x_in   = (const float*)d_in[0];
    const float* pe     = (const float*)d_in[1];
    const float* Lam    = (const float*)d_in[2];
    const float* eattr  = (const float*)d_in[3];
    const float* phi_w1 = (const float*)d_in[4];
    const float* phi_b1 = (const float*)d_in[5];
    const float* phi_w2 = (const float*)d_in[6];
    const float* phi_b2 = (const float*)d_in[7];
    const float* enc_w  = (const float*)d_in[8];
    const float* enc_b  = (const float*)d_in[9];
    const float* lin_w  = (const float*)d_in[10];
    const float* lin_b  = (const float*)d_in[11];
    const float* mlp_w1 = (const float*)d_in[12];
    const float* mlp_b1 = (const float*)d_in[13];
    const float* bn1_g  = (const float*)d_in[14];
    const float* bn1_b  = (const float*)d_in[15];
    const float* mlp_w2 = (const float*)d_in[16];
    const float* mlp_b2 = (const float*)d_in[17];
    const float* bn2_g  = (const float*)d_in[18];
    const float* bn2_b  = (const float*)d_in[19];
    const int* edge_index = (const int*)d_in[20];
    const int* batch      = (const int*)d_in[21];
    float* out = (float*)d_out;

    char* ws = (char*)d_ws;
    size_t off = 0;
    auto alloc = [&](size_t bytes) -> void* {
        void* p = ws + off;
        off += (bytes + 255) & ~(size_t)255;
        return p;
    };
    bf16_t* feat      = (bf16_t*)alloc((size_t)N_EDGES * 128 * 2);
    int4* edat        = (int4*)alloc((size_t)N_EDGES * 16);
    int* row_ptr      = (int*)alloc((size_t)(N_NODES + 1) * 4);
    int* blk          = (int*)alloc(128 * 4);
    int* rank         = (int*)alloc((size_t)N_EDGES * 4);
    // zero-init region (one memset): counts | stats(8-shard) | bar(8-shard)
    int* counts       = (int*)alloc((size_t)N_NODES * 4);
    float* stats      = (float*)alloc((size_t)NL * 2048 * 4); // per layer: s1[8][128], s2[8][128]
    int* bar          = (int*)alloc((size_t)NL * 256 * 4);    // per layer: 8 counters, 128B apart
    size_t zbytes     = (char*)(bar + NL * 256) - (char*)counts;
    float* h          = (float*)alloc((size_t)N_NODES * 64 * 4);
    bf16_t* x_bf      = (bf16_t*)alloc((size_t)N_NODES * 64 * 2);
    bf16_t* w_all     = (bf16_t*)alloc((size_t)NL * NB * QM * 2);
    bf16_t* wcat_frag = (bf16_t*)alloc((size_t)NL * 8192 * 2);
    bf16_t* w1frag    = (bf16_t*)alloc((size_t)NL * 4096 * 2);
    bf16_t* w2frag    = (bf16_t*)alloc((size_t)NL * 4096 * 2);
    float* cvec       = (float*)alloc((size_t)NL * 64 * 4);

    // ---- one-time setup ----
    hipMemsetAsync(counts, 0, zbytes, stream);
    k_count<<<3125, 256, 0, stream>>>(edge_index + N_EDGES, counts, rank);
    k_scan1<<<98, 1024, 0, stream>>>(counts, row_ptr, blk);
    k_scan2<<<1, 128, 0, stream>>>(blk);
    k_scan3<<<98, 1024, 0, stream>>>(blk, row_ptr);
    k_build<<<50000, 256, 0, stream>>>(edge_index, batch, row_ptr, rank, edat,
                                       pe, eattr, feat);
    k_phi<<<50, 256, 0, stream>>>(Lam, phi_w1, phi_b1, phi_w2, phi_b2, w_all);
    k_prep<<<NL, 256, 0, stream>>>(enc_w, enc_b, lin_w, lin_b, mlp_w1, mlp_w2,
                                   wcat_frag, w1frag, w2frag, cvec);

    // ---- layers ----
    k_hinit0<<<3125, 256, 0, stream>>>(x_in, pe, x_bf, h, out + (size_t)N_NODES * 64);
    for (int l = 0; l < NL; l++) {
        float* s1 = stats + (size_t)l * 2048;
        float* s2 = stats + (size_t)l * 2048 + 1024;
        int* bl = bar + (size_t)l * 256;
        k_edge<<<6250, 256, 0, stream>>>(feat, edat, row_ptr,
                                         w_all + (size_t)l * NB * QM,
                                         wcat_frag + (size_t)l * 8192,
                                         cvec + (size_t)l * 64, x_bf, h);
        if (l < NL - 1)
            k_mlp<0><<<NBLK_MLP, 256, 0, stream>>>(
                h, w1frag + (size_t)l * 4096, w2frag + (size_t)l * 4096,
                mlp_b1 + l * 64, bn1_g + l * 64, bn1_b + l * 64,
                mlp_b2 + l * 64, bn2_g + l * 64, bn2_b + l * 64,
                s1, s2, bl, h, x_bf, (float*)nullptr);
        else
            k_mlp<1><<<NBLK_MLP, 256, 0, stream>>>(
                h, w1frag + (size_t)l * 4096, w2frag + (size_t)l * 4096,
                mlp_b1 + l * 64, bn1_g + l * 64, bn1_b + l * 64,
                mlp_b2 + l * 64, bn2_g + l * 64, bn2_b + l * 64,
                s1, s2, bl, h, x_bf, out);
    }
}